// Round 1
// baseline (5154.277 us; speedup 1.0000x reference)
//
#include <hip/hip_runtime.h>
#include <hip/hip_bf16.h>
#include <math.h>

#define EMBED 768
#define E2    384
#define BATCH 128
#define TT    256
#define TT1   64
#define EPSF  1e-5f

__device__ __forceinline__ float gelu_exact(float x) {
    return 0.5f * x * (1.0f + erff(x * 0.70710678f));
}

// ---------------------------------------------------------------------------
// Kernel Z: z = gelu(LN(concat(z_r,z_i) @ fz_w^T + fz_b)) -> zbuf[b][t][o]
// block: (t-tile of 16, batch), 384 threads (thread = o)
// ---------------------------------------------------------------------------
__global__ __launch_bounds__(384) void kz(const float* __restrict__ z_r,
                                          const float* __restrict__ z_i,
                                          const float* __restrict__ fz_w,
                                          const float* __restrict__ fz_b,
                                          const float* __restrict__ ln_g,
                                          const float* __restrict__ ln_b,
                                          float* __restrict__ zbuf) {
    const int b  = blockIdx.y;
    const int t0 = blockIdx.x * 16;
    const int o  = threadIdx.x;          // 0..383
    const int wave = threadIdx.x >> 6;   // 0..5
    const int lane = threadIdx.x & 63;

    __shared__ float tile[16 * 385];
    __shared__ float mu_s[16];
    __shared__ float rs_s[16];

    float acc[16];
#pragma unroll
    for (int t = 0; t < 16; ++t) acc[t] = 0.f;

    const float* wrow = fz_w + (size_t)o * 1536;

#pragma unroll 1
    for (int half = 0; half < 2; ++half) {
        const float* zbase = (half == 0 ? z_r : z_i) + ((size_t)(b * 64 + t0)) * 768;
        const float* wh = wrow + half * 768;
#pragma unroll 1
        for (int q = 0; q < 192; ++q) {
            const int el = q * 4;
            const float4 w4 = *(const float4*)(wh + el);
#pragma unroll
            for (int t = 0; t < 16; ++t) {
                const float* zr = zbase + t * 768 + el;   // wave-uniform -> s_load
                float s = acc[t];
                s = fmaf(w4.x, zr[0], s);
                s = fmaf(w4.y, zr[1], s);
                s = fmaf(w4.z, zr[2], s);
                s = fmaf(w4.w, zr[3], s);
                acc[t] = s;
            }
        }
    }

    const float bias = fz_b[o];
#pragma unroll
    for (int t = 0; t < 16; ++t) acc[t] += bias;

    // stage for LN reductions
#pragma unroll
    for (int t = 0; t < 16; ++t) tile[t * 385 + o] = acc[t];
    __syncthreads();

    // per-row mean/var: 6 waves cover 16 rows
    for (int t = wave; t < 16; t += 6) {
        float s = 0.f, s2 = 0.f;
#pragma unroll
        for (int k = 0; k < 6; ++k) {
            float v = tile[t * 385 + lane + 64 * k];
            s += v;
            s2 += v * v;
        }
#pragma unroll
        for (int off = 32; off >= 1; off >>= 1) {
            s  += __shfl_down(s, off, 64);
            s2 += __shfl_down(s2, off, 64);
        }
        if (lane == 0) {
            float mu = s * (1.0f / 384.0f);
            float var = s2 * (1.0f / 384.0f) - mu * mu;
            mu_s[t] = mu;
            rs_s[t] = 1.0f / sqrtf(var + EPSF);
        }
    }
    __syncthreads();

    const float g  = ln_g[o];
    const float bb = ln_b[o];
#pragma unroll
    for (int t = 0; t < 16; ++t) {
        float v = (acc[t] - mu_s[t]) * rs_s[t] * g + bb;
        v = gelu_exact(v);
        zbuf[((size_t)(b * 64 + t0 + t)) * 384 + o] = v;   // coalesced over o
    }
}

// ---------------------------------------------------------------------------
// Kernel C: cropped 3x3 conv (central 8x8) + BN + gelu + dot with z_f
// grid (96 o-groups, 128 b); 256 threads.
// wave = o within group; lane = e_sub(4 bits)*4 + quad(2 bits)
// thread owns a 4x4 output quadrant tile and channels e ≡ e_sub (mod 16)
// ---------------------------------------------------------------------------
template<int QI>
__device__ __forceinline__ void comp_row(float (&acc)[16],
                                         const float (&R0)[6],
                                         const float (&R1)[6],
                                         const float (&R2)[6],
                                         const float (&wv)[9]) {
#pragma unroll
    for (int qj = 0; qj < 4; ++qj) {
        float s = acc[QI * 4 + qj];
        s = fmaf(R0[qj],     wv[0], s);
        s = fmaf(R0[qj + 1], wv[1], s);
        s = fmaf(R0[qj + 2], wv[2], s);
        s = fmaf(R1[qj],     wv[3], s);
        s = fmaf(R1[qj + 1], wv[4], s);
        s = fmaf(R1[qj + 2], wv[5], s);
        s = fmaf(R2[qj],     wv[6], s);
        s = fmaf(R2[qj + 1], wv[7], s);
        s = fmaf(R2[qj + 2], wv[8], s);
        acc[QI * 4 + qj] = s;
    }
}

__device__ __forceinline__ void load_row(const float* __restrict__ xe,
                                         int absrow, int c0, float (&R)[6]) {
    const float* p = xe + ((size_t)(absrow * 16 + c0)) * 768;
#pragma unroll
    for (int cc = 0; cc < 6; ++cc) R[cc] = p[cc * 768];
}

__global__ __launch_bounds__(256) void kc(const float* __restrict__ x,     // (B,256,768)
                                          const float* __restrict__ w,     // (384,768,3,3)
                                          const float* __restrict__ bc,
                                          const float* __restrict__ bng,
                                          const float* __restrict__ bnb,
                                          const float* __restrict__ bnm,
                                          const float* __restrict__ bnv,
                                          const float* __restrict__ zbuf,  // (B,64,384)
                                          float* __restrict__ part) {      // (128,96)
    const int b    = blockIdx.y;
    const int og   = blockIdx.x;           // 0..95
    const int wave = threadIdx.x >> 6;     // 0..3
    const int lane = threadIdx.x & 63;
    const int o    = og * 4 + wave;
    const int e_sub = lane >> 2;           // 0..15
    const int quad  = lane & 3;            // 0..3
    const int qr = quad >> 1, qc = quad & 1;
    const int r0 = qr * 4 + 3;             // input-patch origin row
    const int c0 = qc * 4 + 3;

    const float* xb    = x + (size_t)b * (256 * 768);
    const float* wbase = w + (size_t)o * (768 * 9);

    float acc[16];
#pragma unroll
    for (int k = 0; k < 16; ++k) acc[k] = 0.f;

    float wv[9];
    float A[6], Bv[6], Cv[6];

#pragma unroll 1
    for (int it = 0; it < 48; ++it) {
        const int e = it * 16 + e_sub;
        const float* wp = wbase + (size_t)e * 9;
#pragma unroll
        for (int k = 0; k < 9; ++k) wv[k] = wp[k];
        const float* xe = xb + e;

        load_row(xe, r0 + 0, c0, A);
        load_row(xe, r0 + 1, c0, Bv);
        load_row(xe, r0 + 2, c0, Cv);
        comp_row<0>(acc, A, Bv, Cv, wv);
        load_row(xe, r0 + 3, c0, A);
        comp_row<1>(acc, Bv, Cv, A, wv);
        load_row(xe, r0 + 4, c0, Bv);
        comp_row<2>(acc, Cv, A, Bv, wv);
        load_row(xe, r0 + 5, c0, Cv);
        comp_row<3>(acc, A, Bv, Cv, wv);
    }

    // reduce over the 16 e_sub lane-groups (lane bits 2..5)
#pragma unroll
    for (int m = 0; m < 4; ++m) {
        const int mask = 4 << m;   // 4,8,16,32
#pragma unroll
        for (int k = 0; k < 16; ++k)
            acc[k] += __shfl_xor(acc[k], mask, 64);
    }

    // BN + gelu + dot with z_f (all lanes redundantly; identical within group)
    const float inv = 1.0f / sqrtf(bnv[o] + EPSF);
    const float gg  = bng[o];
    const float sc  = inv * gg;
    const float sh  = (bc[o] - bnm[o]) * sc + bnb[o];
    const float* zb = zbuf + (size_t)b * 24576 + o;

    float sum = 0.f;
#pragma unroll
    for (int k = 0; k < 16; ++k) {
        const int qi = k >> 2, qj = k & 3;
        const int i = qr * 4 + qi;         // crop-local 0..7
        const int j = qc * 4 + qj;
        float y = fmaf(acc[k], sc, sh);
        float gv = gelu_exact(y);
        sum = fmaf(gv, zb[(i * 8 + j) * 384], sum);
    }
    // reduce over quadrants (lane bits 0..1)
    sum += __shfl_xor(sum, 1, 64);
    sum += __shfl_xor(sum, 2, 64);

    __shared__ float red[4];
    if (lane == 0) red[wave] = sum;
    __syncthreads();
    if (threadIdx.x == 0)
        part[(size_t)b * 96 + og] = red[0] + red[1] + red[2] + red[3];
}

// ---------------------------------------------------------------------------
// Kernel R: out[v] = sigmoid( sum_g part[v][g] / c ),  v = conv*128 + b
// ---------------------------------------------------------------------------
__global__ __launch_bounds__(64) void kr(const float* __restrict__ part,
                                         const float* __restrict__ c,
                                         float* __restrict__ out) {
    const int v = blockIdx.x * 64 + threadIdx.x;   // 0..255
    const float* p = part + (size_t)v * 96;
    float s = 0.f;
#pragma unroll 1
    for (int g = 0; g < 96; ++g) s += p[g];
    out[v] = 1.0f / (1.0f + expf(-s / c[0]));
}

extern "C" void kernel_launch(void* const* d_in, const int* in_sizes, int n_in,
                              void* d_out, int out_size, void* d_ws, size_t ws_size,
                              hipStream_t stream) {
    const float* z_r   = (const float*)d_in[0];
    const float* z_i   = (const float*)d_in[1];
    const float* x_r   = (const float*)d_in[2];
    const float* x_i   = (const float*)d_in[3];
    const float* fz_w  = (const float*)d_in[4];
    const float* fz_b  = (const float*)d_in[5];
    const float* ln_g  = (const float*)d_in[6];
    const float* ln_b  = (const float*)d_in[7];
    const float* wr    = (const float*)d_in[8];
    const float* br    = (const float*)d_in[9];
    const float* bnr_g = (const float*)d_in[10];
    const float* bnr_b = (const float*)d_in[11];
    const float* bnr_m = (const float*)d_in[12];
    const float* bnr_v = (const float*)d_in[13];
    const float* wi    = (const float*)d_in[14];
    const float* bi    = (const float*)d_in[15];
    const float* bni_g = (const float*)d_in[16];
    const float* bni_b = (const float*)d_in[17];
    const float* bni_m = (const float*)d_in[18];
    const float* bni_v = (const float*)d_in[19];
    const float* c     = (const float*)d_in[20];

    float* ws   = (float*)d_ws;
    float* zbuf = ws;                     // 128*64*384 = 3,145,728 f32
    float* part = ws + 3145728;           // 2*128*96  = 24,576 f32

    dim3 gz(4, 128);
    kz<<<gz, 384, 0, stream>>>(z_r, z_i, fz_w, fz_b, ln_g, ln_b, zbuf);

    dim3 gc(96, 128);
    kc<<<gc, 256, 0, stream>>>(x_r, wr, br, bnr_g, bnr_b, bnr_m, bnr_v, zbuf, part);
    kc<<<gc, 256, 0, stream>>>(x_i, wi, bi, bni_g, bni_b, bni_m, bni_v, zbuf, part + 128 * 96);

    kr<<<4, 64, 0, stream>>>(part, c, (float*)d_out);
}

// Round 3
// 524.559 us; speedup vs baseline: 9.8259x; 9.8259x over previous
//
#include <hip/hip_runtime.h>
#include <hip/hip_bf16.h>
#include <math.h>

#define EPSF 1e-5f

typedef __bf16 v8bf __attribute__((ext_vector_type(8)));
typedef float  v4f  __attribute__((ext_vector_type(4)));
typedef unsigned int u32;
typedef unsigned short u16;

__device__ __forceinline__ float gelu_exact(float x) {
    return 0.5f * x * (1.0f + erff(x * 0.70710678f));
}
__device__ __forceinline__ u16 f2bf(float f) {   // RNE
    u32 u = __float_as_uint(f);
    return (u16)((u + 0x7fffu + ((u >> 16) & 1u)) >> 16);
}
__device__ __forceinline__ float bf2f(u16 u) {
    return __uint_as_float(((u32)u) << 16);
}
__device__ __forceinline__ void gload16(const void* g, void* l) {
    __builtin_amdgcn_global_load_lds((const __attribute__((address_space(1))) u32*)g,
                                     (__attribute__((address_space(3))) u32*)l, 16, 0, 0);
}

// ---------------------------------------------------------------------------
// Kernel Z: z = gelu(LN(concat(z_r,z_i) @ fz_w^T + fz_b)) -> zbuf[b][t][o] bf16
// ---------------------------------------------------------------------------
__global__ __launch_bounds__(384) void kz(const float* __restrict__ z_r,
                                          const float* __restrict__ z_i,
                                          const float* __restrict__ fz_w,
                                          const float* __restrict__ fz_b,
                                          const float* __restrict__ ln_g,
                                          const float* __restrict__ ln_b,
                                          u16* __restrict__ zbuf) {
    const int b  = blockIdx.y;
    const int t0 = blockIdx.x * 16;
    const int o  = threadIdx.x;
    const int wave = threadIdx.x >> 6;
    const int lane = threadIdx.x & 63;

    __shared__ float tile[16 * 385];
    __shared__ float mu_s[16];
    __shared__ float rs_s[16];

    float acc[16];
#pragma unroll
    for (int t = 0; t < 16; ++t) acc[t] = 0.f;

    const float* wrow = fz_w + (size_t)o * 1536;

#pragma unroll 1
    for (int half = 0; half < 2; ++half) {
        const float* zbase = (half == 0 ? z_r : z_i) + ((size_t)(b * 64 + t0)) * 768;
        const float* wh = wrow + half * 768;
#pragma unroll 1
        for (int q = 0; q < 192; ++q) {
            const int el = q * 4;
            const float4 w4 = *(const float4*)(wh + el);
#pragma unroll
            for (int t = 0; t < 16; ++t) {
                const float* zr = zbase + t * 768 + el;   // wave-uniform -> s_load
                float s = acc[t];
                s = fmaf(w4.x, zr[0], s);
                s = fmaf(w4.y, zr[1], s);
                s = fmaf(w4.z, zr[2], s);
                s = fmaf(w4.w, zr[3], s);
                acc[t] = s;
            }
        }
    }

    const float bias = fz_b[o];
#pragma unroll
    for (int t = 0; t < 16; ++t) acc[t] += bias;

#pragma unroll
    for (int t = 0; t < 16; ++t) tile[t * 385 + o] = acc[t];
    __syncthreads();

    for (int t = wave; t < 16; t += 6) {
        float s = 0.f, s2 = 0.f;
#pragma unroll
        for (int k = 0; k < 6; ++k) {
            float v = tile[t * 385 + lane + 64 * k];
            s += v; s2 += v * v;
        }
#pragma unroll
        for (int off = 32; off >= 1; off >>= 1) {
            s  += __shfl_down(s, off, 64);
            s2 += __shfl_down(s2, off, 64);
        }
        if (lane == 0) {
            float mu = s * (1.0f / 384.0f);
            float var = s2 * (1.0f / 384.0f) - mu * mu;
            mu_s[t] = mu;
            rs_s[t] = 1.0f / sqrtf(var + EPSF);
        }
    }
    __syncthreads();

    const float g  = ln_g[o];
    const float bb = ln_b[o];
#pragma unroll
    for (int t = 0; t < 16; ++t) {
        float v = (acc[t] - mu_s[t]) * rs_s[t] * g + bb;
        zbuf[((size_t)(b * 64 + t0 + t)) * 384 + o] = f2bf(gelu_exact(v));
    }
}

// ---------------------------------------------------------------------------
// Weight prep: w[o][e][3][3] f32 -> Bw slabs, linear per (conv,s,ec2):
//   slab layout = [h(0..3)][n(0..383)][8 bf16]   (16B per (h,n))
// so kc2 can gload16 it linearly into LDS planes.
// ---------------------------------------------------------------------------
__global__ __launch_bounds__(256) void kprep_w(const float* __restrict__ wr,
                                               const float* __restrict__ wi,
                                               u16* __restrict__ Bw) {
    int idx = blockIdx.x * 256 + threadIdx.x;     // 0 .. 663551
    int n = idx % 384;
    int r = idx / 384;
    int h = r & 3;  r >>= 2;
    int ec2 = r % 24; r /= 24;
    int s = r % 9;
    int conv = r / 9;
    const float* w = conv ? wi : wr;
    const int ch0 = ec2 * 32 + h * 8;
    const float* wp = w + (size_t)n * 6912 + (size_t)ch0 * 9 + s;
    u16 tmp[8];
#pragma unroll
    for (int e = 0; e < 8; ++e) tmp[e] = f2bf(wp[e * 9]);
    size_t slot = (((size_t)(conv * 9 + s) * 24 + ec2) * 1536) + h * 384 + n;
    uint4 pk;
    pk.x = (u32)tmp[0] | ((u32)tmp[1] << 16);
    pk.y = (u32)tmp[2] | ((u32)tmp[3] << 16);
    pk.z = (u32)tmp[4] | ((u32)tmp[5] << 16);
    pk.w = (u32)tmp[6] | ((u32)tmp[7] << 16);
    *(uint4*)(Bw + slot * 8) = pk;
}

// ---------------------------------------------------------------------------
// Kernel C2: implicit-GEMM cropped conv (central 8x8) via 16x16x32 bf16 MFMA,
// fused BN+gelu+dot(z)+sigmoid epilogue.
// grid (128 b, 2 conv), 384 threads = 6 waves. M=64 pixels, N=384, K=6912.
// K-step = 32 channels x 1 tap; 24 ec2-chunks x 9 taps = 216 steps.
// LDS: A double-buffer (per ec2), B double-buffer (per step); one barrier/step.
// A plane-major: [h][row 0..175][16B]; B plane-major: [h][n 0..383][16B].
// ---------------------------------------------------------------------------
#define A_PLANE 2816
#define A_BUF   11264
#define B_BUF   24576

__global__ __launch_bounds__(384, 1) void kc2(const float* __restrict__ x_r,
                                              const float* __restrict__ x_i,
                                              const u16* __restrict__ Bw,
                                              const u16* __restrict__ zbuf,
                                              const float* __restrict__ br,  const float* __restrict__ bnr_g,
                                              const float* __restrict__ bnr_b, const float* __restrict__ bnr_m,
                                              const float* __restrict__ bnr_v,
                                              const float* __restrict__ bi,  const float* __restrict__ bni_g,
                                              const float* __restrict__ bni_b, const float* __restrict__ bni_m,
                                              const float* __restrict__ bni_v,
                                              const float* __restrict__ c,
                                              float* __restrict__ out) {
    const int b    = blockIdx.x;
    const int conv = blockIdx.y;
    const int tid  = threadIdx.x;
    const int lane = tid & 63;
    const int wid  = tid >> 6;          // 0..5 (64-col group)
    const int l15  = lane & 15;
    const int h    = lane >> 4;         // 0..3 k-half

    __shared__ __align__(16) char lds[2 * A_BUF + 2 * B_BUF];
    char* ldsB = lds + 2 * A_BUF;

    const float* x = conv ? x_i : x_r;
    const float* xb = x + (size_t)b * (256 * 768);
    const u16* Bwc = Bw + (size_t)conv * (9 * 24 * 1536 * 8);

    // A-frag base offsets per mi (row0 part); step adds (di*16+dj)*16
    int aoff[4];
#pragma unroll
    for (int mi = 0; mi < 4; ++mi) {
        int p = mi * 16 + l15;          // crop pixel 0..63
        int i = p >> 3, j = p & 7;
        int row0 = i * 16 + j + 3;      // strip-local input row for tap (0,0)
        aoff[mi] = h * A_PLANE + row0 * 16;
    }
    int boff[4];
#pragma unroll
    for (int nj = 0; nj < 4; ++nj) {
        int n = wid * 64 + nj * 16 + l15;
        boff[nj] = h * 6144 + n * 16;
    }

    auto stageB = [&](int ec2, int s, char* buf) {
        const char* src = (const char*)(Bwc + (((size_t)s * 24 + ec2) * 1536) * 8);
#pragma unroll
        for (int k = 0; k < 4; ++k) {
            int sl = tid + k * 384;
            gload16(src + sl * 16, buf + sl * 16);
        }
    };
    auto stageA = [&](int ec2, char* buf) {
        // 1408 slots: 176 rows x 8 float4-quarters (32 ch)
#pragma unroll
        for (int k = 0; k < 4; ++k) {
            int sl = tid + k * 384;
            if (sl < 1408) {
                int row = sl >> 3, qq = sl & 7;
                const float* src = xb + ((size_t)(48 + row)) * 768 + ec2 * 32 + qq * 4;
                float4 v = *(const float4*)src;
                ushort4 pk;
                pk.x = f2bf(v.x); pk.y = f2bf(v.y); pk.z = f2bf(v.z); pk.w = f2bf(v.w);
                *(ushort4*)(buf + (qq >> 1) * A_PLANE + row * 16 + (qq & 1) * 8) = pk;
            }
        }
    };

    v4f acc[4][4] = {};

    stageA(0, lds);
    stageB(0, 0, ldsB);
    __syncthreads();

#pragma unroll 1
    for (int ec2 = 0; ec2 < 24; ++ec2) {
        const int ep = ec2 & 1;
        char* curA = lds + ep * A_BUF;
#pragma unroll
        for (int s = 0; s < 9; ++s) {
            const int tp = ep ^ (s & 1);
            char* curB = ldsB + tp * B_BUF;
            char* nxtB = ldsB + (tp ^ 1) * B_BUF;
            if (s < 8) {
                stageB(ec2, s + 1, nxtB);
            } else if (ec2 < 23) {
                stageB(ec2 + 1, 0, nxtB);
                stageA(ec2 + 1, lds + (ep ^ 1) * A_BUF);
            }
            const int soff = ((s / 3) * 16 + (s % 3)) * 16;
            v8bf a[4], bf[4];
#pragma unroll
            for (int mi = 0; mi < 4; ++mi) a[mi] = *(const v8bf*)(curA + aoff[mi] + soff);
#pragma unroll
            for (int nj = 0; nj < 4; ++nj) bf[nj] = *(const v8bf*)(curB + boff[nj]);
#pragma unroll
            for (int mi = 0; mi < 4; ++mi)
#pragma unroll
                for (int nj = 0; nj < 4; ++nj)
                    acc[mi][nj] = __builtin_amdgcn_mfma_f32_16x16x32_bf16(a[mi], bf[nj], acc[mi][nj], 0, 0, 0);
            __syncthreads();
        }
    }

    // Epilogue: BN + gelu + dot with z, reduce, sigmoid.
    const float* bcp = conv ? bi    : br;
    const float* gp  = conv ? bni_g : bnr_g;
    const float* bbp = conv ? bni_b : bnr_b;
    const float* mp  = conv ? bni_m : bnr_m;
    const float* vp  = conv ? bni_v : bnr_v;
    const u16* zb = zbuf + (size_t)b * 24576;

    float sum = 0.f;
#pragma unroll
    for (int nj = 0; nj < 4; ++nj) {
        const int o = wid * 64 + nj * 16 + l15;
        const float sc = gp[o] * rsqrtf(vp[o] + EPSF);
        const float sh = (bcp[o] - mp[o]) * sc + bbp[o];
#pragma unroll
        for (int mi = 0; mi < 4; ++mi) {
#pragma unroll
            for (int reg = 0; reg < 4; ++reg) {
                int pix = mi * 16 + h * 4 + reg;   // C/D: row=(lane>>4)*4+reg
                float y = fmaf(acc[mi][nj][reg], sc, sh);
                sum = fmaf(gelu_exact(y), bf2f(zb[pix * 384 + o]), sum);
            }
        }
    }
#pragma unroll
    for (int off = 32; off >= 1; off >>= 1) sum += __shfl_down(sum, off, 64);

    __shared__ float red[6];
    if (lane == 0) red[wid] = sum;
    __syncthreads();
    if (tid == 0) {
        float t = red[0] + red[1] + red[2] + red[3] + red[4] + red[5];
        out[conv * 128 + b] = 1.f / (1.f + expf(-t / c[0]));
    }
}

extern "C" void kernel_launch(void* const* d_in, const int* in_sizes, int n_in,
                              void* d_out, int out_size, void* d_ws, size_t ws_size,
                              hipStream_t stream) {
    const float* z_r   = (const float*)d_in[0];
    const float* z_i   = (const float*)d_in[1];
    const float* x_r   = (const float*)d_in[2];
    const float* x_i   = (const float*)d_in[3];
    const float* fz_w  = (const float*)d_in[4];
    const float* fz_b  = (const float*)d_in[5];
    const float* ln_g  = (const float*)d_in[6];
    const float* ln_b  = (const float*)d_in[7];
    const float* wr    = (const float*)d_in[8];
    const float* br    = (const float*)d_in[9];
    const float* bnr_g = (const float*)d_in[10];
    const float* bnr_b = (const float*)d_in[11];
    const float* bnr_m = (const float*)d_in[12];
    const float* bnr_v = (const float*)d_in[13];
    const float* wi    = (const float*)d_in[14];
    const float* bi    = (const float*)d_in[15];
    const float* bni_g = (const float*)d_in[16];
    const float* bni_b = (const float*)d_in[17];
    const float* bni_m = (const float*)d_in[18];
    const float* bni_v = (const float*)d_in[19];
    const float* c     = (const float*)d_in[20];

    // ws (bytes): zbuf bf16 [0, 6291456) | Bw bf16 [6291456, +10616832) = 16.9 MB total
    u16* zbuf = (u16*)d_ws;
    u16* Bw   = (u16*)((char*)d_ws + 6291456);

    kprep_w<<<2592, 256, 0, stream>>>(wr, wi, Bw);
    kz<<<dim3(4, 128), 384, 0, stream>>>(z_r, z_i, fz_w, fz_b, ln_g, ln_b, zbuf);
    kc2<<<dim3(128, 2), 384, 0, stream>>>(x_r, x_i, Bw, zbuf,
                                          br, bnr_g, bnr_b, bnr_m, bnr_v,
                                          bi, bni_g, bni_b, bni_m, bni_v,
                                          c, (float*)d_out);
}

// Round 4
// 319.749 us; speedup vs baseline: 16.1198x; 1.6405x over previous
//
#include <hip/hip_runtime.h>
#include <hip/hip_bf16.h>
#include <math.h>

#define EPSF 1e-5f

typedef __bf16 v8bf __attribute__((ext_vector_type(8)));
typedef float  v4f  __attribute__((ext_vector_type(4)));
typedef unsigned int u32;
typedef unsigned short u16;

__device__ __forceinline__ float gelu_exact(float x) {
    return 0.5f * x * (1.0f + erff(x * 0.70710678f));
}
__device__ __forceinline__ u16 f2bf(float f) {   // RNE
    u32 u = __float_as_uint(f);
    return (u16)((u + 0x7fffu + ((u >> 16) & 1u)) >> 16);
}
__device__ __forceinline__ float bf2f(u16 u) {
    return __uint_as_float(((u32)u) << 16);
}
__device__ __forceinline__ void gload16(const void* g, void* l) {
    __builtin_amdgcn_global_load_lds((const __attribute__((address_space(1))) u32*)g,
                                     (__attribute__((address_space(3))) u32*)l, 16, 0, 0);
}

// ---------------------------------------------------------------------------
// Prep: fz_w[o][1536] f32 -> Bz[ec2][h][n][8] bf16 slabs (gload16-linear)
// ---------------------------------------------------------------------------
__global__ __launch_bounds__(256) void kprep_z(const float* __restrict__ fz_w,
                                               u16* __restrict__ Bz) {
    int idx = blockIdx.x * 256 + threadIdx.x;   // 0 .. 73727
    int n = idx % 384;
    int r = idx / 384;
    int h = r & 3;
    int ec2 = r >> 2;                            // 0..47
    const float* src = fz_w + (size_t)n * 1536 + ec2 * 32 + h * 8;
    float4 v0 = *(const float4*)src;
    float4 v1 = *(const float4*)(src + 4);
    uint4 pk;
    pk.x = (u32)f2bf(v0.x) | ((u32)f2bf(v0.y) << 16);
    pk.y = (u32)f2bf(v0.z) | ((u32)f2bf(v0.w) << 16);
    pk.z = (u32)f2bf(v1.x) | ((u32)f2bf(v1.y) << 16);
    pk.w = (u32)f2bf(v1.z) | ((u32)f2bf(v1.w) << 16);
    *(uint4*)(Bz + (size_t)idx * 8) = pk;
}

// ---------------------------------------------------------------------------
// Prep: w[o][e][3][3] f32 -> Bw[conv][s][ec2][h][n][8] bf16 slabs
// ---------------------------------------------------------------------------
__global__ __launch_bounds__(256) void kprep_w(const float* __restrict__ wr,
                                               const float* __restrict__ wi,
                                               u16* __restrict__ Bw) {
    int idx = blockIdx.x * 256 + threadIdx.x;     // 0 .. 663551
    int n = idx % 384;
    int r = idx / 384;
    int h = r & 3;  r >>= 2;
    int ec2 = r % 24; r /= 24;
    int s = r % 9;
    int conv = r / 9;
    const float* w = conv ? wi : wr;
    const int ch0 = ec2 * 32 + h * 8;
    const float* wp = w + (size_t)n * 6912 + (size_t)ch0 * 9 + s;
    u16 tmp[8];
#pragma unroll
    for (int e = 0; e < 8; ++e) tmp[e] = f2bf(wp[e * 9]);
    size_t slot = (((size_t)(conv * 9 + s) * 24 + ec2) * 4 + h) * 384 + n;
    uint4 pk;
    pk.x = (u32)tmp[0] | ((u32)tmp[1] << 16);
    pk.y = (u32)tmp[2] | ((u32)tmp[3] << 16);
    pk.z = (u32)tmp[4] | ((u32)tmp[5] << 16);
    pk.w = (u32)tmp[6] | ((u32)tmp[7] << 16);
    *(uint4*)(Bw + slot * 8) = pk;
}

// ---------------------------------------------------------------------------
// Fused kernel: [phase 1] z = gelu(LN(z_cat @ fz_w^T + fz_b)) via MFMA,
// kept as register fragments; [phase 2] implicit-GEMM cropped conv;
// [phase 3] BN + gelu + elementwise dot + sigmoid.
// grid (128 b, 2 conv), 384 threads = 6 waves.
// Fragment layout identical across phases: row=(mi*16+h*4+reg) [t or pix],
// col=(wid*64+nj*16+l15) [o].
// ---------------------------------------------------------------------------
#define A_PLANE 2816
#define A_BUF   11264
#define B_BUF   24576
#define ZA_BUF  4096

__global__ __launch_bounds__(384, 1) void kc3(const float* __restrict__ z_r,
                                              const float* __restrict__ z_i,
                                              const u16* __restrict__ Bz,
                                              const float* __restrict__ fz_b,
                                              const float* __restrict__ ln_g,
                                              const float* __restrict__ ln_b,
                                              const float* __restrict__ x_r,
                                              const float* __restrict__ x_i,
                                              const u16* __restrict__ Bw,
                                              const float* __restrict__ br,  const float* __restrict__ bnr_g,
                                              const float* __restrict__ bnr_b, const float* __restrict__ bnr_m,
                                              const float* __restrict__ bnr_v,
                                              const float* __restrict__ bi,  const float* __restrict__ bni_g,
                                              const float* __restrict__ bni_b, const float* __restrict__ bni_m,
                                              const float* __restrict__ bni_v,
                                              const float* __restrict__ c,
                                              float* __restrict__ out) {
    const int b    = blockIdx.x;
    const int conv = blockIdx.y;
    const int tid  = threadIdx.x;
    const int lane = tid & 63;
    const int wid  = tid >> 6;          // 0..5
    const int l15  = lane & 15;
    const int h    = lane >> 4;         // 0..3

    __shared__ __align__(16) char lds[2 * A_BUF + 2 * B_BUF];
    char* ldsB = lds + 2 * A_BUF;
    __shared__ float redS[6][64];
    __shared__ float redQ[6][64];
    __shared__ float mu_s[64], rs_s[64];
    __shared__ float redF[6];

    const float* zr_b = z_r + (size_t)b * (64 * 768);
    const float* zi_b = z_i + (size_t)b * (64 * 768);
    const float* x  = conv ? x_i : x_r;
    const float* xb = x + (size_t)b * (256 * 768);
    const u16* Bwc = Bw + (size_t)conv * ((size_t)9 * 24 * 1536 * 8);

    // ---- fragment offsets ----
    int boff[4];
#pragma unroll
    for (int nj = 0; nj < 4; ++nj) {
        int n = wid * 64 + nj * 16 + l15;
        boff[nj] = h * 6144 + n * 16;
    }
    int zaoff[4];     // phase-1 A: [h][t(64)][16B]
#pragma unroll
    for (int mi = 0; mi < 4; ++mi)
        zaoff[mi] = h * 1024 + (mi * 16 + l15) * 16;
    int aoff[4];      // phase-2 A: [h][row(176)][16B], +tap offset
#pragma unroll
    for (int mi = 0; mi < 4; ++mi) {
        int p = mi * 16 + l15;
        int i = p >> 3, j = p & 7;
        aoff[mi] = h * A_PLANE + (i * 16 + j + 3) * 16;
    }

    // ---- staging lambdas ----
    auto stageZB = [&](int ec2, char* buf) {
        const char* src = (const char*)(Bz + (size_t)ec2 * 1536 * 8);
#pragma unroll
        for (int k = 0; k < 4; ++k) {
            int sl = tid + k * 384;
            gload16(src + sl * 16, buf + sl * 16);
        }
    };
    auto stageZA = [&](int ec2, char* buf) {
        const float* zsrc = (ec2 < 24) ? zr_b : zi_b;
        const int ch0 = (ec2 < 24 ? ec2 : ec2 - 24) * 32;
#pragma unroll
        for (int k = 0; k < 2; ++k) {
            int sl = tid + k * 384;
            if (sl < 512) {
                int row = sl >> 3, qq = sl & 7;
                float4 v = *(const float4*)(zsrc + (size_t)row * 768 + ch0 + qq * 4);
                ushort4 pk;
                pk.x = f2bf(v.x); pk.y = f2bf(v.y); pk.z = f2bf(v.z); pk.w = f2bf(v.w);
                *(ushort4*)(buf + (qq >> 1) * 1024 + row * 16 + (qq & 1) * 8) = pk;
            }
        }
    };
    auto stageB = [&](int ec2, int s, char* buf) {
        const char* src = (const char*)(Bwc + (((size_t)s * 24 + ec2) * 1536) * 8);
#pragma unroll
        for (int k = 0; k < 4; ++k) {
            int sl = tid + k * 384;
            gload16(src + sl * 16, buf + sl * 16);
        }
    };
    auto stageA = [&](int ec2, char* buf) {
#pragma unroll
        for (int k = 0; k < 4; ++k) {
            int sl = tid + k * 384;
            if (sl < 1408) {
                int row = sl >> 3, qq = sl & 7;
                float4 v = *(const float4*)(xb + (size_t)(48 + row) * 768 + ec2 * 32 + qq * 4);
                ushort4 pk;
                pk.x = f2bf(v.x); pk.y = f2bf(v.y); pk.z = f2bf(v.z); pk.w = f2bf(v.w);
                *(ushort4*)(buf + (qq >> 1) * A_PLANE + row * 16 + (qq & 1) * 8) = pk;
            }
        }
    };

    v4f acc[4][4] = {};

    // ================= phase 1: z GEMM (48 K-steps) =================
    stageZA(0, lds);
    stageZB(0, ldsB);
    __syncthreads();
#pragma unroll 1
    for (int ec2 = 0; ec2 < 48; ++ec2) {
        const int p = ec2 & 1;
        char* curA = lds + p * ZA_BUF;
        char* curB = ldsB + p * B_BUF;
        if (ec2 < 47) {
            stageZA(ec2 + 1, lds + (p ^ 1) * ZA_BUF);
            stageZB(ec2 + 1, ldsB + (p ^ 1) * B_BUF);
        }
        v8bf a[4], bf[4];
#pragma unroll
        for (int mi = 0; mi < 4; ++mi) a[mi] = *(const v8bf*)(curA + zaoff[mi]);
#pragma unroll
        for (int nj = 0; nj < 4; ++nj) bf[nj] = *(const v8bf*)(curB + boff[nj]);
#pragma unroll
        for (int mi = 0; mi < 4; ++mi)
#pragma unroll
            for (int nj = 0; nj < 4; ++nj)
                acc[mi][nj] = __builtin_amdgcn_mfma_f32_16x16x32_bf16(a[mi], bf[nj], acc[mi][nj], 0, 0, 0);
        __syncthreads();
    }

    // ---- bias + LN stats ----
    float fzb[4], lng[4], lnb[4];
#pragma unroll
    for (int nj = 0; nj < 4; ++nj) {
        int o = wid * 64 + nj * 16 + l15;
        fzb[nj] = fz_b[o]; lng[nj] = ln_g[o]; lnb[nj] = ln_b[o];
    }
#pragma unroll
    for (int mi = 0; mi < 4; ++mi)
#pragma unroll
        for (int nj = 0; nj < 4; ++nj)
#pragma unroll
            for (int reg = 0; reg < 4; ++reg)
                acc[mi][nj][reg] += fzb[nj];

#pragma unroll
    for (int mi = 0; mi < 4; ++mi) {
#pragma unroll
        for (int reg = 0; reg < 4; ++reg) {
            float s = 0.f, q = 0.f;
#pragma unroll
            for (int nj = 0; nj < 4; ++nj) {
                float v = acc[mi][nj][reg];
                s += v; q += v * v;
            }
#pragma unroll
            for (int m = 0; m < 4; ++m) {
                s += __shfl_xor(s, 1 << m, 64);
                q += __shfl_xor(q, 1 << m, 64);
            }
            if (l15 == 0) {
                int row = mi * 16 + h * 4 + reg;
                redS[wid][row] = s;
                redQ[wid][row] = q;
            }
        }
    }
    __syncthreads();
    if (tid < 64) {
        float s = 0.f, q = 0.f;
#pragma unroll
        for (int w6 = 0; w6 < 6; ++w6) { s += redS[w6][tid]; q += redQ[w6][tid]; }
        float mu = s * (1.0f / 384.0f);
        float var = q * (1.0f / 384.0f) - mu * mu;
        mu_s[tid] = mu;
        rs_s[tid] = rsqrtf(var + EPSF);
    }
    __syncthreads();

    // ---- LN + gelu -> packed bf16 z fragments ----
    u32 zpk[4][4][2];
#pragma unroll
    for (int mi = 0; mi < 4; ++mi)
#pragma unroll
        for (int nj = 0; nj < 4; ++nj)
#pragma unroll
            for (int rp = 0; rp < 2; ++rp) {
                float zv[2];
#pragma unroll
                for (int k = 0; k < 2; ++k) {
                    int reg = rp * 2 + k;
                    int row = mi * 16 + h * 4 + reg;
                    float v = (acc[mi][nj][reg] - mu_s[row]) * rs_s[row] * lng[nj] + lnb[nj];
                    zv[k] = gelu_exact(v);
                }
                zpk[mi][nj][rp] = (u32)f2bf(zv[0]) | ((u32)f2bf(zv[1]) << 16);
            }

    // ================= phase 2: conv GEMM (24 x 9 steps) =================
    v4f zero4 = {0.f, 0.f, 0.f, 0.f};
#pragma unroll
    for (int mi = 0; mi < 4; ++mi)
#pragma unroll
        for (int nj = 0; nj < 4; ++nj) acc[mi][nj] = zero4;

    __syncthreads();   // everyone done reading phase-1 LDS
    stageA(0, lds);
    stageB(0, 0, ldsB);
    __syncthreads();

#pragma unroll 1
    for (int ec2 = 0; ec2 < 24; ++ec2) {
        const int ep = ec2 & 1;
        char* curA = lds + ep * A_BUF;
#pragma unroll
        for (int s = 0; s < 9; ++s) {
            const int tp = ep ^ (s & 1);
            char* curB = ldsB + tp * B_BUF;
            char* nxtB = ldsB + (tp ^ 1) * B_BUF;
            if (s < 8) {
                stageB(ec2, s + 1, nxtB);
            } else if (ec2 < 23) {
                stageB(ec2 + 1, 0, nxtB);
                stageA(ec2 + 1, lds + (ep ^ 1) * A_BUF);
            }
            const int soff = ((s / 3) * 16 + (s % 3)) * 16;
            v8bf a[4], bf[4];
#pragma unroll
            for (int mi = 0; mi < 4; ++mi) a[mi] = *(const v8bf*)(curA + aoff[mi] + soff);
#pragma unroll
            for (int nj = 0; nj < 4; ++nj) bf[nj] = *(const v8bf*)(curB + boff[nj]);
#pragma unroll
            for (int mi = 0; mi < 4; ++mi)
#pragma unroll
                for (int nj = 0; nj < 4; ++nj)
                    acc[mi][nj] = __builtin_amdgcn_mfma_f32_16x16x32_bf16(a[mi], bf[nj], acc[mi][nj], 0, 0, 0);
            __syncthreads();
        }
    }

    // ================= phase 3: BN + gelu + dot + sigmoid =================
    const float* bcp = conv ? bi    : br;
    const float* gp  = conv ? bni_g : bnr_g;
    const float* bbp = conv ? bni_b : bnr_b;
    const float* mp  = conv ? bni_m : bnr_m;
    const float* vp  = conv ? bni_v : bnr_v;

    float sum = 0.f;
#pragma unroll
    for (int nj = 0; nj < 4; ++nj) {
        const int o = wid * 64 + nj * 16 + l15;
        const float sc = gp[o] * rsqrtf(vp[o] + EPSF);
        const float sh = (bcp[o] - mp[o]) * sc + bbp[o];
#pragma unroll
        for (int mi = 0; mi < 4; ++mi) {
#pragma unroll
            for (int reg = 0; reg < 4; ++reg) {
                float y = fmaf(acc[mi][nj][reg], sc, sh);
                u32 zw = zpk[mi][nj][reg >> 1];
                float zv = bf2f((u16)((reg & 1) ? (zw >> 16) : (zw & 0xffff)));
                sum = fmaf(gelu_exact(y), zv, sum);
            }
        }
    }
#pragma unroll
    for (int off = 32; off >= 1; off >>= 1) sum += __shfl_down(sum, off, 64);

    if (lane == 0) redF[wid] = sum;
    __syncthreads();
    if (tid == 0) {
        float t = redF[0] + redF[1] + redF[2] + redF[3] + redF[4] + redF[5];
        out[conv * 128 + b] = 1.f / (1.f + expf(-t / c[0]));
    }
}

extern "C" void kernel_launch(void* const* d_in, const int* in_sizes, int n_in,
                              void* d_out, int out_size, void* d_ws, size_t ws_size,
                              hipStream_t stream) {
    const float* z_r   = (const float*)d_in[0];
    const float* z_i   = (const float*)d_in[1];
    const float* x_r   = (const float*)d_in[2];
    const float* x_i   = (const float*)d_in[3];
    const float* fz_w  = (const float*)d_in[4];
    const float* fz_b  = (const float*)d_in[5];
    const float* ln_g  = (const float*)d_in[6];
    const float* ln_b  = (const float*)d_in[7];
    const float* wr    = (const float*)d_in[8];
    const float* br    = (const float*)d_in[9];
    const float* bnr_g = (const float*)d_in[10];
    const float* bnr_b = (const float*)d_in[11];
    const float* bnr_m = (const float*)d_in[12];
    const float* bnr_v = (const float*)d_in[13];
    const float* wi    = (const float*)d_in[14];
    const float* bi    = (const float*)d_in[15];
    const float* bni_g = (const float*)d_in[16];
    const float* bni_b = (const float*)d_in[17];
    const float* bni_m = (const float*)d_in[18];
    const float* bni_v = (const float*)d_in[19];
    const float* c     = (const float*)d_in[20];

    // ws (bytes): Bz [0, 1179648) | Bw [1179648, +10616832)  = 11.8 MB
    u16* Bz = (u16*)d_ws;
    u16* Bw = (u16*)((char*)d_ws + 1179648);

    kprep_z<<<288, 256, 0, stream>>>(fz_w, Bz);
    kprep_w<<<2592, 256, 0, stream>>>(wr, wi, Bw);
    kc3<<<dim3(128, 2), 384, 0, stream>>>(z_r, z_i, Bz, fz_b, ln_g, ln_b,
                                          x_r, x_i, Bw,
                                          br, bnr_g, bnr_b, bnr_m, bnr_v,
                                          bi, bni_g, bni_b, bni_m, bni_v,
                                          c, (float*)d_out);
}

// Round 5
// 235.431 us; speedup vs baseline: 21.8930x; 1.3581x over previous
//
#include <hip/hip_runtime.h>
#include <hip/hip_bf16.h>
#include <math.h>

#define EPSF 1e-5f

typedef __bf16 v8bf __attribute__((ext_vector_type(8)));
typedef float  v4f  __attribute__((ext_vector_type(4)));
typedef unsigned int u32;
typedef unsigned short u16;

__device__ __forceinline__ float gelu_exact(float x) {
    return 0.5f * x * (1.0f + erff(x * 0.70710678f));
}
__device__ __forceinline__ u16 f2bf(float f) {   // RNE
    u32 u = __float_as_uint(f);
    return (u16)((u + 0x7fffu + ((u >> 16) & 1u)) >> 16);
}
__device__ __forceinline__ float bf2f(u16 u) {
    return __uint_as_float(((u32)u) << 16);
}
__device__ __forceinline__ void gload16(const void* g, void* l) {
    __builtin_amdgcn_global_load_lds((const __attribute__((address_space(1))) u32*)g,
                                     (__attribute__((address_space(3))) u32*)l, 16, 0, 0);
}

// counted-vmcnt barrier: allow N vector-mem ops outstanding, drain LDS ops.
#define BARRIER(N) do { \
    asm volatile("s_waitcnt vmcnt(" #N ") lgkmcnt(0)" ::: "memory"); \
    __builtin_amdgcn_s_barrier(); \
} while (0)

// ---------------------------------------------------------------------------
// Prep: fz_w[o][1536] f32 -> Bz[ec2][h][n][8] bf16 (coalesced reads)
// ---------------------------------------------------------------------------
__global__ __launch_bounds__(256) void kprep_z(const float* __restrict__ fz_w,
                                               u16* __restrict__ Bz) {
    int idx = blockIdx.x * 256 + threadIdx.x;   // 0 .. 73727
    int n = idx / 192;
    int r = idx % 192;
    int ec2 = r >> 2;
    int h = r & 3;
    const float* src = fz_w + (size_t)n * 1536 + ec2 * 32 + h * 8;
    float4 v0 = *(const float4*)src;
    float4 v1 = *(const float4*)(src + 4);
    uint4 pk;
    pk.x = (u32)f2bf(v0.x) | ((u32)f2bf(v0.y) << 16);
    pk.y = (u32)f2bf(v0.z) | ((u32)f2bf(v0.w) << 16);
    pk.z = (u32)f2bf(v1.x) | ((u32)f2bf(v1.y) << 16);
    pk.w = (u32)f2bf(v1.z) | ((u32)f2bf(v1.w) << 16);
    size_t slot = ((size_t)(ec2 * 4 + h) * 384 + n);
    *(uint4*)(Bz + slot * 8) = pk;
}

// ---------------------------------------------------------------------------
// Prep: w[n][e][3][3] f32 -> Bw[conv][s][ec2][h][n][8] bf16.
// One block per (n, conv): coalesced 27KB read into LDS, scatter-pack out.
// ---------------------------------------------------------------------------
__global__ __launch_bounds__(256) void kprep_w(const float* __restrict__ wr,
                                               const float* __restrict__ wi,
                                               u16* __restrict__ Bw) {
    __shared__ float wsm[6912];
    const int tid = threadIdx.x;
    const int n = blockIdx.x >> 1;
    const int conv = blockIdx.x & 1;
    const float* w = (conv ? wi : wr) + (size_t)n * 6912;
#pragma unroll
    for (int k = 0; k < 7; ++k) {
        int sl = tid + k * 256;
        if (sl < 1728) ((float4*)wsm)[sl] = ((const float4*)w)[sl];
    }
    __syncthreads();
#pragma unroll
    for (int k = 0; k < 4; ++k) {
        int sl = tid + k * 256;          // (s*24+ec2)*4 + h
        if (sl < 864) {
            int h = sl & 3;
            int r = sl >> 2;
            int ec2 = r % 24;
            int s = r / 24;
            int ch0 = ec2 * 32 + h * 8;
            u16 tmp[8];
#pragma unroll
            for (int e = 0; e < 8; ++e) tmp[e] = f2bf(wsm[(ch0 + e) * 9 + s]);
            uint4 pk;
            pk.x = (u32)tmp[0] | ((u32)tmp[1] << 16);
            pk.y = (u32)tmp[2] | ((u32)tmp[3] << 16);
            pk.z = (u32)tmp[4] | ((u32)tmp[5] << 16);
            pk.w = (u32)tmp[6] | ((u32)tmp[7] << 16);
            size_t slot = ((size_t)conv * 864 + sl) * 384 + n;
            *(uint4*)(Bw + slot * 8) = pk;
        }
    }
}

// ---------------------------------------------------------------------------
// Fused kernel, deep-pipelined (counted vmcnt, 3-buffer B, T14 reg-staging).
// grid (128 b, 2 conv), 384 threads = 6 waves.
// ---------------------------------------------------------------------------
#define A_PLANE 2816
#define A_BUF   11264
#define B_BUF   24576
#define ZA_BUF  4096

__global__ __launch_bounds__(384, 1) void kc3(const float* __restrict__ z_r,
                                              const float* __restrict__ z_i,
                                              const u16* __restrict__ Bz,
                                              const float* __restrict__ fz_b,
                                              const float* __restrict__ ln_g,
                                              const float* __restrict__ ln_b,
                                              const float* __restrict__ x_r,
                                              const float* __restrict__ x_i,
                                              const u16* __restrict__ Bw,
                                              const float* __restrict__ br,  const float* __restrict__ bnr_g,
                                              const float* __restrict__ bnr_b, const float* __restrict__ bnr_m,
                                              const float* __restrict__ bnr_v,
                                              const float* __restrict__ bi,  const float* __restrict__ bni_g,
                                              const float* __restrict__ bni_b, const float* __restrict__ bni_m,
                                              const float* __restrict__ bni_v,
                                              const float* __restrict__ c,
                                              float* __restrict__ out) {
    const int b    = blockIdx.x;
    const int conv = blockIdx.y;
    const int tid  = threadIdx.x;
    const int lane = tid & 63;
    const int wid  = tid >> 6;          // 0..5
    const int l15  = lane & 15;
    const int h    = lane >> 4;         // 0..3

    __shared__ __align__(16) char lds[3 * B_BUF + 2 * A_BUF];   // 96256 B
    char* ldsB  = lds;                     // 3 x B_BUF
    char* ldsA  = lds + 3 * B_BUF;         // 2 x A_BUF ; phase-1: ZA bufs in Abuf0
    float* redS = (float*)(ldsA + A_BUF);  // aliases Abuf1 (safe: first A-write there is ec2=1)
    float* redQ = redS + 384;
    float* mu_s = redQ + 384;
    float* rs_s = mu_s + 64;
    float* redF = (float*)lds;             // aliases Bbuf0 (safe at end: last B reads hit buf2)

    const float* zr_b = z_r + (size_t)b * (64 * 768);
    const float* zi_b = z_i + (size_t)b * (64 * 768);
    const float* x  = conv ? x_i : x_r;
    const float* xb = x + (size_t)b * (256 * 768);
    const u16* Bwc = Bw + (size_t)conv * ((size_t)864 * 384 * 8);

    // ---- fragment offsets ----
    int boff[4];
#pragma unroll
    for (int nj = 0; nj < 4; ++nj) {
        int n = wid * 64 + nj * 16 + l15;
        boff[nj] = h * 6144 + n * 16;
    }
    int zaoff[4];
#pragma unroll
    for (int mi = 0; mi < 4; ++mi)
        zaoff[mi] = h * 1024 + (mi * 16 + l15) * 16;
    int aoff[4];
#pragma unroll
    for (int mi = 0; mi < 4; ++mi) {
        int p = mi * 16 + l15;
        int i = p >> 3, j = p & 7;
        aoff[mi] = h * A_PLANE + (i * 16 + j + 3) * 16;
    }

    // ---- staging helpers ----
    auto stageZB = [&](int ec2, char* buf) {       // 4 gload16 / thread
        const char* src = (const char*)(Bz + (size_t)ec2 * 1536 * 8);
#pragma unroll
        for (int k = 0; k < 4; ++k) {
            int sl = tid + k * 384;
            gload16(src + sl * 16, buf + sl * 16);
        }
    };
    auto stageB = [&](int ec2, int s, char* buf) { // 4 gload16 / thread
        const char* src = (const char*)(Bwc + (((size_t)s * 24 + ec2) * 1536) * 8);
#pragma unroll
        for (int k = 0; k < 4; ++k) {
            int sl = tid + k * 384;
            gload16(src + sl * 16, buf + sl * 16);
        }
    };
    auto issueZA = [&](int ec2, float4* zr) {      // 2 global loads / thread (uniform)
        const float* zsrc = (ec2 < 24) ? zr_b : zi_b;
        const int ch0 = (ec2 < 24 ? ec2 : ec2 - 24) * 32;
        int sl0 = tid;
        int sl1 = (tid < 128) ? tid + 384 : tid;
        zr[0] = *(const float4*)(zsrc + (size_t)(sl0 >> 3) * 768 + ch0 + (sl0 & 7) * 4);
        zr[1] = *(const float4*)(zsrc + (size_t)(sl1 >> 3) * 768 + ch0 + (sl1 & 7) * 4);
    };
    auto convertZA = [&](const float4* zr, char* buf) {
#pragma unroll
        for (int k = 0; k < 2; ++k) {
            int sl = (k == 0) ? tid : ((tid < 128) ? tid + 384 : tid);
            int row = sl >> 3, qq = sl & 7;
            ushort4 pk;
            pk.x = f2bf(zr[k].x); pk.y = f2bf(zr[k].y);
            pk.z = f2bf(zr[k].z); pk.w = f2bf(zr[k].w);
            *(ushort4*)(buf + (qq >> 1) * 1024 + row * 16 + (qq & 1) * 8) = pk;
        }
    };
    auto issueA = [&](int ec2, float4* ar) {       // 4 global loads / thread (uniform)
#pragma unroll
        for (int k = 0; k < 4; ++k) {
            int sl = tid + k * 384;
            if (sl >= 1408) sl -= 1408;
            int row = sl >> 3, qq = sl & 7;
            ar[k] = *(const float4*)(xb + (size_t)(48 + row) * 768 + ec2 * 32 + qq * 4);
        }
    };
    auto convertA = [&](const float4* ar, char* buf) {
#pragma unroll
        for (int k = 0; k < 4; ++k) {
            int sl = tid + k * 384;
            if (sl >= 1408) sl -= 1408;
            int row = sl >> 3, qq = sl & 7;
            ushort4 pk;
            pk.x = f2bf(ar[k].x); pk.y = f2bf(ar[k].y);
            pk.z = f2bf(ar[k].z); pk.w = f2bf(ar[k].w);
            *(ushort4*)(buf + (qq >> 1) * A_PLANE + row * 16 + (qq & 1) * 8) = pk;
        }
    };

    v4f acc[4][4] = {};

    auto comp = [&](char* curA, const int* aof, int soff, char* curB) {
        v8bf a[4], bfv[4];
#pragma unroll
        for (int mi = 0; mi < 4; ++mi) a[mi] = *(const v8bf*)(curA + aof[mi] + soff);
#pragma unroll
        for (int nj = 0; nj < 4; ++nj) bfv[nj] = *(const v8bf*)(curB + boff[nj]);
        __builtin_amdgcn_s_setprio(1);
#pragma unroll
        for (int mi = 0; mi < 4; ++mi)
#pragma unroll
            for (int nj = 0; nj < 4; ++nj)
                acc[mi][nj] = __builtin_amdgcn_mfma_f32_16x16x32_bf16(a[mi], bfv[nj], acc[mi][nj], 0, 0, 0);
        __builtin_amdgcn_s_setprio(0);
    };

    // ================= phase 1: z GEMM, 48 steps, pipelined =================
    float4 zreg[2];
    {
        issueZA(0, zreg);
        stageZB(0, ldsB);
        stageZB(1, ldsB + B_BUF);
        convertZA(zreg, ldsA);          // compiler waits zreg (vmcnt(8))
        issueZA(1, zreg);
        BARRIER(6);                     // allow ZB(1)=4 + ZA(1)=2
    }
#pragma unroll 2
    for (int t = 0; t < 46; ++t) {
        char* curZB = ldsB + (t % 3) * B_BUF;
        char* nxtZB = ldsB + ((t + 2) % 3) * B_BUF;
        char* curZA = ldsA + (t & 1) * ZA_BUF;
        char* nxtZA = ldsA + ((t + 1) & 1) * ZA_BUF;
        stageZB(t + 2, nxtZB);
        comp(curZA, zaoff, 0, curZB);
        convertZA(zreg, nxtZA);         // zreg = ZA(t+1); waits vmcnt(4)
        issueZA(t + 2, zreg);
        BARRIER(10);                    // ZB(t+1)4 + ZB(t+2)4 + ZA(t+2)2
    }
    {   // t = 46
        comp(ldsA, zaoff, 0, ldsB + (46 % 3) * B_BUF);
        convertZA(zreg, ldsA + ZA_BUF); // ZA(47)
        BARRIER(4);                     // ZB(47) outstanding
    }
    {   // t = 47
        comp(ldsA + ZA_BUF, zaoff, 0, ldsB + (47 % 3) * B_BUF);
    }

    // ---- bias + LN stats ----
    float fzb[4], lng[4], lnb[4];
#pragma unroll
    for (int nj = 0; nj < 4; ++nj) {
        int o = wid * 64 + nj * 16 + l15;
        fzb[nj] = fz_b[o]; lng[nj] = ln_g[o]; lnb[nj] = ln_b[o];
    }
#pragma unroll
    for (int mi = 0; mi < 4; ++mi)
#pragma unroll
        for (int nj = 0; nj < 4; ++nj)
#pragma unroll
            for (int reg = 0; reg < 4; ++reg)
                acc[mi][nj][reg] += fzb[nj];

#pragma unroll
    for (int mi = 0; mi < 4; ++mi) {
#pragma unroll
        for (int reg = 0; reg < 4; ++reg) {
            float s = 0.f, q = 0.f;
#pragma unroll
            for (int nj = 0; nj < 4; ++nj) {
                float v = acc[mi][nj][reg];
                s += v; q += v * v;
            }
#pragma unroll
            for (int m = 0; m < 4; ++m) {
                s += __shfl_xor(s, 1 << m, 64);
                q += __shfl_xor(q, 1 << m, 64);
            }
            if (l15 == 0) {
                int row = mi * 16 + h * 4 + reg;
                redS[wid * 64 + row] = s;
                redQ[wid * 64 + row] = q;
            }
        }
    }
    __syncthreads();
    if (tid < 64) {
        float s = 0.f, q = 0.f;
#pragma unroll
        for (int w6 = 0; w6 < 6; ++w6) { s += redS[w6 * 64 + tid]; q += redQ[w6 * 64 + tid]; }
        float mu = s * (1.0f / 384.0f);
        float var = q * (1.0f / 384.0f) - mu * mu;
        mu_s[tid] = mu;
        rs_s[tid] = rsqrtf(var + EPSF);
    }
    __syncthreads();

    // ---- LN + gelu -> packed bf16 z fragments ----
    u32 zpk[4][4][2];
#pragma unroll
    for (int mi = 0; mi < 4; ++mi)
#pragma unroll
        for (int nj = 0; nj < 4; ++nj)
#pragma unroll
            for (int rp = 0; rp < 2; ++rp) {
                float zv[2];
#pragma unroll
                for (int k = 0; k < 2; ++k) {
                    int reg = rp * 2 + k;
                    int row = mi * 16 + h * 4 + reg;
                    float v = (acc[mi][nj][reg] - mu_s[row]) * rs_s[row] * lng[nj] + lnb[nj];
                    zv[k] = gelu_exact(v);
                }
                zpk[mi][nj][rp] = (u32)f2bf(zv[0]) | ((u32)f2bf(zv[1]) << 16);
            }

    // ================= phase 2: conv GEMM, 216 steps, pipelined =================
    v4f zero4 = {0.f, 0.f, 0.f, 0.f};
#pragma unroll
    for (int mi = 0; mi < 4; ++mi)
#pragma unroll
        for (int nj = 0; nj < 4; ++nj) acc[mi][nj] = zero4;

    float4 areg[4];
    {
        issueA(0, areg);
        stageB(0, 0, ldsB);
        stageB(0, 1, ldsB + B_BUF);
        convertA(areg, ldsA);           // compiler waits areg (vmcnt(8))
        BARRIER(4);                     // B(0,1) outstanding
    }

#pragma unroll 1
    for (int ec2 = 0; ec2 < 23; ++ec2) {
        char* A_cur = ldsA + (ec2 & 1) * A_BUF;
        char* A_nxt = ldsA + ((ec2 + 1) & 1) * A_BUF;
#pragma unroll
        for (int s = 0; s < 9; ++s) {
            if (s < 7) stageB(ec2, s + 2, ldsB + ((s + 2) % 3) * B_BUF);
            else       stageB(ec2 + 1, s - 7, ldsB + ((s + 2) % 3) * B_BUF);
            if (s == 4) issueA(ec2 + 1, areg);
            const int soff = ((s / 3) * 16 + (s % 3)) * 16;
            comp(A_cur, aoff, soff, ldsB + (s % 3) * B_BUF);
            if (s == 7) convertA(areg, A_nxt);
            if (s == 4 || s == 5 || s == 6) BARRIER(12);   // +areg in flight
            else                            BARRIER(8);
        }
    }
    {   // ec2 = 23 (tail)
        char* A_cur = ldsA + A_BUF;
#pragma unroll
        for (int s = 0; s < 9; ++s) {
            if (s < 7) stageB(23, s + 2, ldsB + ((s + 2) % 3) * B_BUF);
            const int soff = ((s / 3) * 16 + (s % 3)) * 16;
            comp(A_cur, aoff, soff, ldsB + (s % 3) * B_BUF);
            if (s < 7)       BARRIER(8);
            else if (s == 7) BARRIER(4);
            // s == 8: fall through to epilogue (no barrier needed; redF aliases Bbuf0,
            // while the last compute reads Bbuf2/Abuf1 only)
        }
    }

    // ================= phase 3: BN + gelu + dot + sigmoid =================
    const float* bcp = conv ? bi    : br;
    const float* gp  = conv ? bni_g : bnr_g;
    const float* bbp = conv ? bni_b : bnr_b;
    const float* mp  = conv ? bni_m : bnr_m;
    const float* vp  = conv ? bni_v : bnr_v;

    float sum = 0.f;
#pragma unroll
    for (int nj = 0; nj < 4; ++nj) {
        const int o = wid * 64 + nj * 16 + l15;
        const float sc = gp[o] * rsqrtf(vp[o] + EPSF);
        const float sh = (bcp[o] - mp[o]) * sc + bbp[o];
#pragma unroll
        for (int mi = 0; mi < 4; ++mi) {
#pragma unroll
            for (int reg = 0; reg < 4; ++reg) {
                float y = fmaf(acc[mi][nj][reg], sc, sh);
                u32 zw = zpk[mi][nj][reg >> 1];
                float zv = bf2f((u16)((reg & 1) ? (zw >> 16) : (zw & 0xffff)));
                sum = fmaf(gelu_exact(y), zv, sum);
            }
        }
    }
#pragma unroll
    for (int off = 32; off >= 1; off >>= 1) sum += __shfl_down(sum, off, 64);

    if (lane == 0) redF[wid] = sum;
    __syncthreads();
    if (tid == 0) {
        float t = redF[0] + redF[1] + redF[2] + redF[3] + redF[4] + redF[5];
        out[conv * 128 + b] = 1.f / (1.f + expf(-t / c[0]));
    }
}

extern "C" void kernel_launch(void* const* d_in, const int* in_sizes, int n_in,
                              void* d_out, int out_size, void* d_ws, size_t ws_size,
                              hipStream_t stream) {
    const float* z_r   = (const float*)d_in[0];
    const float* z_i   = (const float*)d_in[1];
    const float* x_r   = (const float*)d_in[2];
    const float* x_i   = (const float*)d_in[3];
    const float* fz_w  = (const float*)d_in[4];
    const float* fz_b  = (const float*)d_in[5];
    const float* ln_g  = (const float*)d_in[6];
    const float* ln_b  = (const float*)d_in[7];
    const float* wr    = (const float*)d_in[8];
    const float* br    = (const float*)d_in[9];
    const float* bnr_g = (const float*)d_in[10];
    const float* bnr_b = (const float*)d_in[11];
    const float* bnr_m = (const float*)d_in[12];
    const float* bnr_v = (const float*)d_in[13];
    const float* wi    = (const float*)d_in[14];
    const float* bi    = (const float*)d_in[15];
    const float* bni_g = (const float*)d_in[16];
    const float* bni_b = (const float*)d_in[17];
    const float* bni_m = (const float*)d_in[18];
    const float* bni_v = (const float*)d_in[19];
    const float* c     = (const float*)d_in[20];

    // ws (bytes): Bz [0, 1179648) | Bw [1179648, +10616832)  = 11.8 MB
    u16* Bz = (u16*)d_ws;
    u16* Bw = (u16*)((char*)d_ws + 1179648);

    kprep_z<<<288, 256, 0, stream>>>(fz_w, Bz);
    kprep_w<<<768, 256, 0, stream>>>(wr, wi, Bw);
    kc3<<<dim3(128, 2), 384, 0, stream>>>(z_r, z_i, Bz, fz_b, ln_g, ln_b,
                                          x_r, x_i, Bw,
                                          br, bnr_g, bnr_b, bnr_m, bnr_v,
                                          bi, bni_g, bni_b, bni_m, bni_v,
                                          c, (float*)d_out);
}

// Round 7
// 228.613 us; speedup vs baseline: 22.5458x; 1.0298x over previous
//
#include <hip/hip_runtime.h>
#include <hip/hip_bf16.h>
#include <math.h>

#define EPSF 1e-5f

typedef __bf16 v8bf __attribute__((ext_vector_type(8)));
typedef float  v4f  __attribute__((ext_vector_type(4)));
typedef unsigned int u32;
typedef unsigned short u16;

__device__ __forceinline__ float gelu_exact(float x) {
    return 0.5f * x * (1.0f + erff(x * 0.70710678f));
}
__device__ __forceinline__ u16 f2bf(float f) {   // RNE
    u32 u = __float_as_uint(f);
    return (u16)((u + 0x7fffu + ((u >> 16) & 1u)) >> 16);
}
__device__ __forceinline__ float bf2f(u16 u) {
    return __uint_as_float(((u32)u) << 16);
}
__device__ __forceinline__ void gload16(const void* g, void* l) {
    __builtin_amdgcn_global_load_lds((const __attribute__((address_space(1))) u32*)g,
                                     (__attribute__((address_space(3))) u32*)l, 16, 0, 0);
}

// counted-vmcnt barrier: allow N vector-mem ops outstanding, drain LDS ops.
#define BARRIER(N) do { \
    asm volatile("s_waitcnt vmcnt(" #N ") lgkmcnt(0)" ::: "memory"); \
    __builtin_amdgcn_s_barrier(); \
} while (0)

// ---------------------------------------------------------------------------
// Prep: fz_w[o][1536] f32 -> Bz[ec2][h][n][8] bf16 (coalesced reads)
// ---------------------------------------------------------------------------
__global__ __launch_bounds__(256) void kprep_z(const float* __restrict__ fz_w,
                                               u16* __restrict__ Bz) {
    int idx = blockIdx.x * 256 + threadIdx.x;   // 0 .. 73727
    int n = idx / 192;
    int r = idx % 192;
    int ec2 = r >> 2;
    int h = r & 3;
    const float* src = fz_w + (size_t)n * 1536 + ec2 * 32 + h * 8;
    float4 v0 = *(const float4*)src;
    float4 v1 = *(const float4*)(src + 4);
    uint4 pk;
    pk.x = (u32)f2bf(v0.x) | ((u32)f2bf(v0.y) << 16);
    pk.y = (u32)f2bf(v0.z) | ((u32)f2bf(v0.w) << 16);
    pk.z = (u32)f2bf(v1.x) | ((u32)f2bf(v1.y) << 16);
    pk.w = (u32)f2bf(v1.z) | ((u32)f2bf(v1.w) << 16);
    size_t slot = ((size_t)(ec2 * 4 + h) * 384 + n);
    *(uint4*)(Bz + slot * 8) = pk;
}

// ---------------------------------------------------------------------------
// Prep: w[n][e][3][3] f32 -> Bw[conv][s][ec2][h][n][8] bf16.
// ---------------------------------------------------------------------------
__global__ __launch_bounds__(256) void kprep_w(const float* __restrict__ wr,
                                               const float* __restrict__ wi,
                                               u16* __restrict__ Bw) {
    __shared__ float wsm[6912];
    const int tid = threadIdx.x;
    const int n = blockIdx.x >> 1;
    const int conv = blockIdx.x & 1;
    const float* w = (conv ? wi : wr) + (size_t)n * 6912;
#pragma unroll
    for (int k = 0; k < 7; ++k) {
        int sl = tid + k * 256;
        if (sl < 1728) ((float4*)wsm)[sl] = ((const float4*)w)[sl];
    }
    __syncthreads();
#pragma unroll
    for (int k = 0; k < 4; ++k) {
        int sl = tid + k * 256;          // (s*24+ec2)*4 + h
        if (sl < 864) {
            int h = sl & 3;
            int r = sl >> 2;
            int ec2 = r % 24;
            int s = r / 24;
            int ch0 = ec2 * 32 + h * 8;
            u16 tmp[8];
#pragma unroll
            for (int e = 0; e < 8; ++e) tmp[e] = f2bf(wsm[(ch0 + e) * 9 + s]);
            uint4 pk;
            pk.x = (u32)tmp[0] | ((u32)tmp[1] << 16);
            pk.y = (u32)tmp[2] | ((u32)tmp[3] << 16);
            pk.z = (u32)tmp[4] | ((u32)tmp[5] << 16);
            pk.w = (u32)tmp[6] | ((u32)tmp[7] << 16);
            size_t slot = ((size_t)conv * 864 + sl) * 384 + n;
            *(uint4*)(Bw + slot * 8) = pk;
        }
    }
}

// ---------------------------------------------------------------------------
// kz2: z = gelu(LN(concat(z_r,z_i) @ fz_w^T + fz_b)) via MFMA.
// grid (2 t-halves, 128 b), 384 thr = 6 waves. M=32, N=384, K=1536 (48 steps).
// Writes zpk[b][o][t(64)] bf16.
// ---------------------------------------------------------------------------
#define ZB_BUF 24576
#define ZA_BUF 2048

__global__ __launch_bounds__(384, 1) void kz2(const float* __restrict__ z_r,
                                              const float* __restrict__ z_i,
                                              const u16* __restrict__ Bz,
                                              const float* __restrict__ fz_b,
                                              const float* __restrict__ ln_g,
                                              const float* __restrict__ ln_b,
                                              u16* __restrict__ zpk) {
    const int th = blockIdx.x;
    const int b  = blockIdx.y;
    const int tid  = threadIdx.x;
    const int lane = tid & 63;
    const int wid  = tid >> 6;
    const int l15  = lane & 15;
    const int h    = lane >> 4;

    __shared__ __align__(16) char lds[3 * ZB_BUF + 2 * ZA_BUF];   // 77824
    char* ldsZB = lds;
    char* ldsZA = lds + 3 * ZB_BUF;
    __shared__ float redS[6 * 32], redQ[6 * 32], mu_s[32], rs_s[32];

    const float* zr_b = z_r + (size_t)b * (64 * 768);
    const float* zi_b = z_i + (size_t)b * (64 * 768);

    int boff[4];
#pragma unroll
    for (int nj = 0; nj < 4; ++nj) {
        int n = wid * 64 + nj * 16 + l15;
        boff[nj] = h * 6144 + n * 16;
    }
    int zaoff[2];
#pragma unroll
    for (int mi = 0; mi < 2; ++mi)
        zaoff[mi] = h * 512 + (mi * 16 + l15) * 16;

    auto stageZB = [&](int ec2, char* buf) {       // 4 gload16 / thread
        const char* src = (const char*)(Bz + (size_t)ec2 * 1536 * 8);
#pragma unroll
        for (int k = 0; k < 4; ++k) {
            int sl = tid + k * 384;
            gload16(src + sl * 16, buf + sl * 16);
        }
    };
    auto issueZA = [&](int ec2, float4* zr) {      // 1 load / thread (uniform)
        const float* zsrc = (ec2 < 24) ? zr_b : zi_b;
        const int ch0 = (ec2 < 24 ? ec2 : ec2 - 24) * 32;
        int sl = tid & 255;
        int row = sl >> 3, qq = sl & 7;
        zr[0] = *(const float4*)(zsrc + (size_t)(th * 32 + row) * 768 + ch0 + qq * 4);
    };
    auto convertZA = [&](const float4* zr, char* buf) {
        int sl = tid & 255;
        int row = sl >> 3, qq = sl & 7;
        ushort4 pk;
        pk.x = f2bf(zr[0].x); pk.y = f2bf(zr[0].y);
        pk.z = f2bf(zr[0].z); pk.w = f2bf(zr[0].w);
        *(ushort4*)(buf + (qq >> 1) * 512 + row * 16 + (qq & 1) * 8) = pk;
    };

    v4f acc[2][4] = {};

    auto comp = [&](char* curA, char* curB) {
        v8bf a[2], bfv[4];
#pragma unroll
        for (int mi = 0; mi < 2; ++mi) a[mi] = *(const v8bf*)(curA + zaoff[mi]);
#pragma unroll
        for (int nj = 0; nj < 4; ++nj) bfv[nj] = *(const v8bf*)(curB + boff[nj]);
        __builtin_amdgcn_s_setprio(1);
#pragma unroll
        for (int mi = 0; mi < 2; ++mi)
#pragma unroll
            for (int nj = 0; nj < 4; ++nj)
                acc[mi][nj] = __builtin_amdgcn_mfma_f32_16x16x32_bf16(a[mi], bfv[nj], acc[mi][nj], 0, 0, 0);
        __builtin_amdgcn_s_setprio(0);
    };

    float4 zreg[1];
    {
        issueZA(0, zreg);
        stageZB(0, ldsZB);
        stageZB(1, ldsZB + ZB_BUF);
        convertZA(zreg, ldsZA);      // waits ZA(0)
        issueZA(1, zreg);
        BARRIER(5);                  // allow ZB(1)=4 + ZA(1)=1
    }
#pragma unroll 1
    for (int t = 0; t < 46; ++t) {
        stageZB(t + 2, ldsZB + ((t + 2) % 3) * ZB_BUF);
        comp(ldsZA + (t & 1) * ZA_BUF, ldsZB + (t % 3) * ZB_BUF);
        convertZA(zreg, ldsZA + ((t + 1) & 1) * ZA_BUF);  // waits ZA(t+1): vmcnt(4)
        issueZA(t + 2, zreg);
        BARRIER(5);                  // allow ZB(t+2)=4 + ZA(t+2)=1; drains ZB(t+1)
    }
    {   // t = 46
        comp(ldsZA + (46 & 1) * ZA_BUF, ldsZB + (46 % 3) * ZB_BUF);
        convertZA(zreg, ldsZA + (47 & 1) * ZA_BUF);       // waits ZA(47): vmcnt(0)
        BARRIER(0);
    }
    comp(ldsZA + (47 & 1) * ZA_BUF, ldsZB + (47 % 3) * ZB_BUF);

    // ---- bias + LN stats (rows 0..31 local) ----
    float fzb[4], lng[4], lnb[4];
#pragma unroll
    for (int nj = 0; nj < 4; ++nj) {
        int o = wid * 64 + nj * 16 + l15;
        fzb[nj] = fz_b[o]; lng[nj] = ln_g[o]; lnb[nj] = ln_b[o];
    }
#pragma unroll
    for (int mi = 0; mi < 2; ++mi)
#pragma unroll
        for (int nj = 0; nj < 4; ++nj)
#pragma unroll
            for (int reg = 0; reg < 4; ++reg)
                acc[mi][nj][reg] += fzb[nj];

#pragma unroll
    for (int mi = 0; mi < 2; ++mi) {
#pragma unroll
        for (int reg = 0; reg < 4; ++reg) {
            float s = 0.f, q = 0.f;
#pragma unroll
            for (int nj = 0; nj < 4; ++nj) {
                float v = acc[mi][nj][reg];
                s += v; q += v * v;
            }
#pragma unroll
            for (int m = 0; m < 4; ++m) {
                s += __shfl_xor(s, 1 << m, 64);
                q += __shfl_xor(q, 1 << m, 64);
            }
            if (l15 == 0) {
                int row = mi * 16 + h * 4 + reg;
                redS[wid * 32 + row] = s;
                redQ[wid * 32 + row] = q;
            }
        }
    }
    __syncthreads();
    if (tid < 32) {
        float s = 0.f, q = 0.f;
#pragma unroll
        for (int w6 = 0; w6 < 6; ++w6) { s += redS[w6 * 32 + tid]; q += redQ[w6 * 32 + tid]; }
        float mu = s * (1.0f / 384.0f);
        float var = q * (1.0f / 384.0f) - mu * mu;
        mu_s[tid] = mu;
        rs_s[tid] = rsqrtf(var + EPSF);
    }
    __syncthreads();

    // ---- LN + gelu -> zpk[b][o][t] ----
#pragma unroll
    for (int mi = 0; mi < 2; ++mi)
#pragma unroll
        for (int nj = 0; nj < 4; ++nj) {
            int o = wid * 64 + nj * 16 + l15;
            u32* dst = (u32*)zpk + ((size_t)b * 384 + o) * 32 + th * 16 + mi * 8 + h * 2;
#pragma unroll
            for (int rp = 0; rp < 2; ++rp) {
                float zv[2];
#pragma unroll
                for (int k = 0; k < 2; ++k) {
                    int reg = rp * 2 + k;
                    int row = mi * 16 + h * 4 + reg;
                    float v = (acc[mi][nj][reg] - mu_s[row]) * rs_s[row] * lng[nj] + lnb[nj];
                    zv[k] = gelu_exact(v);
                }
                dst[rp] = (u32)f2bf(zv[0]) | ((u32)f2bf(zv[1]) << 16);
            }
        }
}

// ---------------------------------------------------------------------------
// kc4: implicit-GEMM cropped conv, N-split, 4-deep B pipeline.
// grid (4 = conv*2+nh, 128 b), 384 thr = 6 waves. M=64, N=192, K=6912.
// LDS 70 KB -> 2 blocks/CU -> 3 waves/SIMD.
// ---------------------------------------------------------------------------
#define A_PLANE 2816
#define A_BUF   11264
#define BB      12288

__global__ __launch_bounds__(384, 3) void kc4(const float* __restrict__ x_r,
                                              const float* __restrict__ x_i,
                                              const u16* __restrict__ Bw,
                                              const u16* __restrict__ zpk,
                                              const float* __restrict__ br,  const float* __restrict__ bnr_g,
                                              const float* __restrict__ bnr_b, const float* __restrict__ bnr_m,
                                              const float* __restrict__ bnr_v,
                                              const float* __restrict__ bi,  const float* __restrict__ bni_g,
                                              const float* __restrict__ bni_b, const float* __restrict__ bni_m,
                                              const float* __restrict__ bni_v,
                                              float* __restrict__ part) {
    const int q    = blockIdx.x;        // conv*2 + nh
    const int conv = q >> 1;
    const int nh   = q & 1;
    const int b    = blockIdx.y;
    const int tid  = threadIdx.x;
    const int lane = tid & 63;
    const int wid  = tid >> 6;          // 0..5
    const int l15  = lane & 15;
    const int h    = lane >> 4;         // 0..3

    __shared__ __align__(16) char lds[4 * BB + 2 * A_BUF];   // 71680
    char* ldsB = lds;
    char* ldsA = lds + 4 * BB;
    float* redF = (float*)lds;          // reused after final syncthreads

    const float* x  = conv ? x_i : x_r;
    const float* xb = x + (size_t)b * (256 * 768);
    const u16* Bwc = Bw + (size_t)conv * ((size_t)864 * 384 * 8);

    int boff[2];
#pragma unroll
    for (int nj = 0; nj < 2; ++nj) {
        int nl = wid * 32 + nj * 16 + l15;
        boff[nj] = h * 3072 + nl * 16;
    }
    int aoff[4];
#pragma unroll
    for (int mi = 0; mi < 4; ++mi) {
        int p = mi * 16 + l15;
        int i = p >> 3, j = p & 7;
        aoff[mi] = h * A_PLANE + (i * 16 + j + 3) * 16;
    }

    const int hh = (tid >= 192) ? 1 : 0;
    const int nl_st = tid - hh * 192;

    auto stageB = [&](int ec2, int s, char* buf) {   // 2 gload16 / thread
        const char* src = (const char*)(Bwc + (((size_t)s * 24 + ec2) * 1536) * 8);
#pragma unroll
        for (int k = 0; k < 2; ++k) {
            int hplane = k * 2 + hh;
            gload16(src + ((size_t)(hplane * 384 + nh * 192 + nl_st)) * 16,
                    buf + (tid + k * 384) * 16);
        }
    };
    auto issueA = [&](int ec2, float4* ar) {         // 4 loads / thread (uniform)
#pragma unroll
        for (int k = 0; k < 4; ++k) {
            int sl = tid + k * 384;
            if (sl >= 1408) sl -= 1408;
            int row = sl >> 3, qq = sl & 7;
            ar[k] = *(const float4*)(xb + (size_t)(48 + row) * 768 + ec2 * 32 + qq * 4);
        }
    };
    auto convertA = [&](const float4* ar, char* buf) {
#pragma unroll
        for (int k = 0; k < 4; ++k) {
            int sl = tid + k * 384;
            if (sl >= 1408) sl -= 1408;
            int row = sl >> 3, qq = sl & 7;
            ushort4 pk;
            pk.x = f2bf(ar[k].x); pk.y = f2bf(ar[k].y);
            pk.z = f2bf(ar[k].z); pk.w = f2bf(ar[k].w);
            *(ushort4*)(buf + (qq >> 1) * A_PLANE + row * 16 + (qq & 1) * 8) = pk;
        }
    };

    v4f acc[4][2] = {};

    auto comp = [&](char* curA, int soff, char* curB) {
        v8bf a[4], bfv[2];
#pragma unroll
        for (int mi = 0; mi < 4; ++mi) a[mi] = *(const v8bf*)(curA + aoff[mi] + soff);
#pragma unroll
        for (int nj = 0; nj < 2; ++nj) bfv[nj] = *(const v8bf*)(curB + boff[nj]);
        __builtin_amdgcn_s_setprio(1);
#pragma unroll
        for (int mi = 0; mi < 4; ++mi)
#pragma unroll
            for (int nj = 0; nj < 2; ++nj)
                acc[mi][nj] = __builtin_amdgcn_mfma_f32_16x16x32_bf16(a[mi], bfv[nj], acc[mi][nj], 0, 0, 0);
        __builtin_amdgcn_s_setprio(0);
    };

    float4 areg[4];
    {
        issueA(0, areg);
        stageB(0, 0, ldsB);
        stageB(0, 1, ldsB + BB);
        stageB(0, 2, ldsB + 2 * BB);
        convertA(areg, ldsA);        // waits areg: vmcnt(6)
        BARRIER(4);                  // allow B(1),B(2); drains B(0)
    }

#pragma unroll 1
    for (int ec2 = 0; ec2 < 23; ++ec2) {
        char* A_cur = ldsA + (ec2 & 1) * A_BUF;
        char* A_nxt = ldsA + ((ec2 + 1) & 1) * A_BUF;
#pragma unroll
        for (int s = 0; s < 9; ++s) {
            {   // stage B(g+3)
                int e2 = (s <= 5) ? ec2 : ec2 + 1;
                int s2 = (s <= 5) ? s + 3 : s - 6;
                stageB(e2, s2, ldsB + ((ec2 + s + 3) & 3) * BB);
            }
            if (s == 4) issueA(ec2 + 1, areg);
            comp(A_cur, ((s / 3) * 16 + (s % 3)) * 16, ldsB + ((ec2 + s) & 3) * BB);
            if (s == 7) convertA(areg, A_nxt);      // waits areg: vmcnt(6)
            if (s >= 4 && s <= 6) BARRIER(8);       // B(g+2)+B(g+3)+areg
            else                  BARRIER(4);       // B(g+2)+B(g+3)
        }
    }
    {   // ec2 = 23 tail
        char* A_cur = ldsA + (23 & 1) * A_BUF;
#pragma unroll
        for (int s = 0; s < 9; ++s) {
            if (s <= 5) stageB(23, s + 3, ldsB + ((23 + s + 3) & 3) * BB);
            comp(A_cur, ((s / 3) * 16 + (s % 3)) * 16, ldsB + ((23 + s) & 3) * BB);
            if (s <= 5)       BARRIER(4);
            else if (s == 6)  BARRIER(2);
            else if (s == 7)  BARRIER(0);
        }
    }
    __syncthreads();   // all waves done with LDS; redF reuse safe

    // ---- BN + gelu + dot(zpk) ----
    const float* bcp = conv ? bi    : br;
    const float* gp  = conv ? bni_g : bnr_g;
    const float* bbp = conv ? bni_b : bnr_b;
    const float* mp  = conv ? bni_m : bnr_m;
    const float* vp  = conv ? bni_v : bnr_v;

    float sum = 0.f;
#pragma unroll
    for (int nj = 0; nj < 2; ++nj) {
        const int o = nh * 192 + wid * 32 + nj * 16 + l15;
        const float sc = gp[o] * rsqrtf(vp[o] + EPSF);
        const float sh = (bcp[o] - mp[o]) * sc + bbp[o];
        const u16* zb = zpk + ((size_t)b * 384 + o) * 64;
#pragma unroll
        for (int mi = 0; mi < 4; ++mi) {
            ushort4 zw = *(const ushort4*)(zb + mi * 16 + h * 4);
#pragma unroll
            for (int reg = 0; reg < 4; ++reg) {
                float y = fmaf(acc[mi][nj][reg], sc, sh);
                u16 zu = (reg == 0) ? zw.x : (reg == 1) ? zw.y : (reg == 2) ? zw.z : zw.w;
                sum = fmaf(gelu_exact(y), bf2f(zu), sum);
            }
        }
    }
#pragma unroll
    for (int off = 32; off >= 1; off >>= 1) sum += __shfl_down(sum, off, 64);

    if (lane == 0) redF[wid] = sum;
    __syncthreads();
    if (tid == 0) {
        float t = redF[0] + redF[1] + redF[2] + redF[3] + redF[4] + redF[5];
        part[((size_t)conv * 128 + b) * 2 + nh] = t;
    }
}

// ---------------------------------------------------------------------------
// kr: combine n-half partials, sigmoid.
// ---------------------------------------------------------------------------
__global__ __launch_bounds__(256) void kr(const float* __restrict__ part,
                                          const float* __restrict__ c,
                                          float* __restrict__ out) {
    int v = threadIdx.x;     // 0..255 = conv*128+b
    float s = part[v * 2] + part[v * 2 + 1];
    out[v] = 1.f / (1.f + expf(-s / c[0]));
}

extern "C" void kernel_launch(void* const* d_in, const int* in_sizes, int n_in,
                              void* d_out, int out_size, void* d_ws, size_t ws_size,
                              hipStream_t stream) {
    const float* z_r   = (const float*)d_in[0];
    const float* z_i   = (const float*)d_in[1];
    const float* x_r   = (const float*)d_in[2];
    const float* x_i   = (const float*)d_in[3];
    const float* fz_w  = (const float*)d_in[4];
    const float* fz_b  = (const float*)d_in[5];
    const float* ln_g  = (const float*)d_in[6];
    const float* ln_b  = (const float*)d_in[7];
    const float* wr    = (const float*)d_in[8];
    const float* br    = (const float*)d_in[9];
    const float* bnr_g = (const float*)d_in[10];
    const float* bnr_b = (const float*)d_in[11];
    const float* bnr_m = (const float*)d_in[12];
    const float* bnr_v = (const float*)d_in[13];
    const float* wi    = (const float*)d_in[14];
    const float* bi    = (const float*)d_in[15];
    const float* bni_g = (const float*)d_in[16];
    const float* bni_b = (const float*)d_in[17];
    const float* bni_m = (const float*)d_in[18];
    const float* bni_v = (const float*)d_in[19];
    const float* c     = (const float*)d_in[20];

    // ws (bytes): Bz [0, 1179648) | Bw [+10616832) | zpk [+6291456) | part [+2048)
    u16*   Bz   = (u16*)d_ws;
    u16*   Bw   = (u16*)((char*)d_ws + 1179648);
    u16*   zpk  = (u16*)((char*)d_ws + 1179648 + 10616832);
    float* part = (float*)((char*)d_ws + 1179648 + 10616832 + 6291456);

    kprep_z<<<288, 256, 0, stream>>>(fz_w, Bz);
    kprep_w<<<768, 256, 0, stream>>>(wr, wi, Bw);
    kz2<<<dim3(2, 128), 384, 0, stream>>>(z_r, z_i, Bz, fz_b, ln_g, ln_b, zpk);
    kc4<<<dim3(4, 128), 384, 0, stream>>>(x_r, x_i, Bw, zpk,
                                          br, bnr_g, bnr_b, bnr_m, bnr_v,
                                          bi, bni_g, bni_b, bni_m, bni_v,
                                          part);
    kr<<<1, 256, 0, stream>>>(part, c, (float*)d_out);
}

// Round 8
// 213.464 us; speedup vs baseline: 24.1459x; 1.0710x over previous
//
#include <hip/hip_runtime.h>
#include <hip/hip_bf16.h>
#include <math.h>

#define EPSF 1e-5f

typedef __bf16 v8bf __attribute__((ext_vector_type(8)));
typedef float  v4f  __attribute__((ext_vector_type(4)));
typedef unsigned int u32;
typedef unsigned short u16;

__device__ __forceinline__ float gelu_exact(float x) {
    return 0.5f * x * (1.0f + erff(x * 0.70710678f));
}
__device__ __forceinline__ u16 f2bf(float f) {   // RNE
    u32 u = __float_as_uint(f);
    return (u16)((u + 0x7fffu + ((u >> 16) & 1u)) >> 16);
}
__device__ __forceinline__ float bf2f(u16 u) {
    return __uint_as_float(((u32)u) << 16);
}
__device__ __forceinline__ void gload16(const void* g, void* l) {
    __builtin_amdgcn_global_load_lds((const __attribute__((address_space(1))) u32*)g,
                                     (__attribute__((address_space(3))) u32*)l, 16, 0, 0);
}

// counted-vmcnt barrier: allow N vector-mem ops outstanding, drain LDS ops.
#define BARRIER(N) do { \
    asm volatile("s_waitcnt vmcnt(" #N ") lgkmcnt(0)" ::: "memory"); \
    __builtin_amdgcn_s_barrier(); \
} while (0)

// ---------------------------------------------------------------------------
// Prep: fz_w[o][1536] f32 -> Bz[ec2][h][n][8] bf16 (coalesced reads)
// ---------------------------------------------------------------------------
__global__ __launch_bounds__(256) void kprep_z(const float* __restrict__ fz_w,
                                               u16* __restrict__ Bz) {
    int idx = blockIdx.x * 256 + threadIdx.x;   // 0 .. 73727
    int n = idx / 192;
    int r = idx % 192;
    int ec2 = r >> 2;
    int h = r & 3;
    const float* src = fz_w + (size_t)n * 1536 + ec2 * 32 + h * 8;
    float4 v0 = *(const float4*)src;
    float4 v1 = *(const float4*)(src + 4);
    uint4 pk;
    pk.x = (u32)f2bf(v0.x) | ((u32)f2bf(v0.y) << 16);
    pk.y = (u32)f2bf(v0.z) | ((u32)f2bf(v0.w) << 16);
    pk.z = (u32)f2bf(v1.x) | ((u32)f2bf(v1.y) << 16);
    pk.w = (u32)f2bf(v1.z) | ((u32)f2bf(v1.w) << 16);
    size_t slot = ((size_t)(ec2 * 4 + h) * 384 + n);
    *(uint4*)(Bz + slot * 8) = pk;
}

// ---------------------------------------------------------------------------
// Prep: w[n][e][3][3] f32 -> Bw[conv][s][ec2][h][n][8] bf16.
// ---------------------------------------------------------------------------
__global__ __launch_bounds__(256) void kprep_w(const float* __restrict__ wr,
                                               const float* __restrict__ wi,
                                               u16* __restrict__ Bw) {
    __shared__ float wsm[6912];
    const int tid = threadIdx.x;
    const int n = blockIdx.x >> 1;
    const int conv = blockIdx.x & 1;
    const float* w = (conv ? wi : wr) + (size_t)n * 6912;
#pragma unroll
    for (int k = 0; k < 7; ++k) {
        int sl = tid + k * 256;
        if (sl < 1728) ((float4*)wsm)[sl] = ((const float4*)w)[sl];
    }
    __syncthreads();
#pragma unroll
    for (int k = 0; k < 4; ++k) {
        int sl = tid + k * 256;          // (s*24+ec2)*4 + h
        if (sl < 864) {
            int h = sl & 3;
            int r = sl >> 2;
            int ec2 = r % 24;
            int s = r / 24;
            int ch0 = ec2 * 32 + h * 8;
            u16 tmp[8];
#pragma unroll
            for (int e = 0; e < 8; ++e) tmp[e] = f2bf(wsm[(ch0 + e) * 9 + s]);
            uint4 pk;
            pk.x = (u32)tmp[0] | ((u32)tmp[1] << 16);
            pk.y = (u32)tmp[2] | ((u32)tmp[3] << 16);
            pk.z = (u32)tmp[4] | ((u32)tmp[5] << 16);
            pk.w = (u32)tmp[6] | ((u32)tmp[7] << 16);
            size_t slot = ((size_t)conv * 864 + sl) * 384 + n;
            *(uint4*)(Bw + slot * 8) = pk;
        }
    }
}

// ---------------------------------------------------------------------------
// kz2: z = gelu(LN(concat(z_r,z_i) @ fz_w^T + fz_b)) via MFMA.
// grid (2 t-halves, 128 b), 384 thr = 6 waves. Writes zpk[b][o][t(64)] bf16.
// ---------------------------------------------------------------------------
#define ZB_BUF 24576
#define ZA_BUF 2048

__global__ __launch_bounds__(384, 1) void kz2(const float* __restrict__ z_r,
                                              const float* __restrict__ z_i,
                                              const u16* __restrict__ Bz,
                                              const float* __restrict__ fz_b,
                                              const float* __restrict__ ln_g,
                                              const float* __restrict__ ln_b,
                                              u16* __restrict__ zpk) {
    const int th = blockIdx.x;
    const int b  = blockIdx.y;
    const int tid  = threadIdx.x;
    const int lane = tid & 63;
    const int wid  = tid >> 6;
    const int l15  = lane & 15;
    const int h    = lane >> 4;

    __shared__ __align__(16) char lds[3 * ZB_BUF + 2 * ZA_BUF];   // 77824
    char* ldsZB = lds;
    char* ldsZA = lds + 3 * ZB_BUF;
    __shared__ float redS[6 * 32], redQ[6 * 32], mu_s[32], rs_s[32];

    const float* zr_b = z_r + (size_t)b * (64 * 768);
    const float* zi_b = z_i + (size_t)b * (64 * 768);

    int boff[4];
#pragma unroll
    for (int nj = 0; nj < 4; ++nj) {
        int n = wid * 64 + nj * 16 + l15;
        boff[nj] = h * 6144 + n * 16;
    }
    int zaoff[2];
#pragma unroll
    for (int mi = 0; mi < 2; ++mi)
        zaoff[mi] = h * 512 + (mi * 16 + l15) * 16;

    auto stageZB = [&](int ec2, char* buf) {       // 4 gload16 / thread
        const char* src = (const char*)(Bz + (size_t)ec2 * 1536 * 8);
#pragma unroll
        for (int k = 0; k < 4; ++k) {
            int sl = tid + k * 384;
            gload16(src + sl * 16, buf + sl * 16);
        }
    };
    auto issueZA = [&](int ec2, float4* zr) {      // 1 load / thread (uniform)
        const float* zsrc = (ec2 < 24) ? zr_b : zi_b;
        const int ch0 = (ec2 < 24 ? ec2 : ec2 - 24) * 32;
        int sl = tid & 255;
        int row = sl >> 3, qq = sl & 7;
        zr[0] = *(const float4*)(zsrc + (size_t)(th * 32 + row) * 768 + ch0 + qq * 4);
    };
    auto convertZA = [&](const float4* zr, char* buf) {
        int sl = tid & 255;
        int row = sl >> 3, qq = sl & 7;
        ushort4 pk;
        pk.x = f2bf(zr[0].x); pk.y = f2bf(zr[0].y);
        pk.z = f2bf(zr[0].z); pk.w = f2bf(zr[0].w);
        *(ushort4*)(buf + (qq >> 1) * 512 + row * 16 + (qq & 1) * 8) = pk;
    };

    v4f acc[2][4] = {};

    auto comp = [&](char* curA, char* curB) {
        v8bf a[2], bfv[4];
#pragma unroll
        for (int mi = 0; mi < 2; ++mi) a[mi] = *(const v8bf*)(curA + zaoff[mi]);
#pragma unroll
        for (int nj = 0; nj < 4; ++nj) bfv[nj] = *(const v8bf*)(curB + boff[nj]);
        __builtin_amdgcn_s_setprio(1);
#pragma unroll
        for (int mi = 0; mi < 2; ++mi)
#pragma unroll
            for (int nj = 0; nj < 4; ++nj)
                acc[mi][nj] = __builtin_amdgcn_mfma_f32_16x16x32_bf16(a[mi], bfv[nj], acc[mi][nj], 0, 0, 0);
        __builtin_amdgcn_s_setprio(0);
    };

    float4 zreg[1];
    {
        issueZA(0, zreg);
        stageZB(0, ldsZB);
        stageZB(1, ldsZB + ZB_BUF);
        convertZA(zreg, ldsZA);      // waits ZA(0)
        issueZA(1, zreg);
        BARRIER(5);                  // allow ZB(1)=4 + ZA(1)=1
    }
#pragma unroll 1
    for (int t = 0; t < 46; ++t) {
        stageZB(t + 2, ldsZB + ((t + 2) % 3) * ZB_BUF);
        comp(ldsZA + (t & 1) * ZA_BUF, ldsZB + (t % 3) * ZB_BUF);
        convertZA(zreg, ldsZA + ((t + 1) & 1) * ZA_BUF);  // waits ZA(t+1): vmcnt(4)
        issueZA(t + 2, zreg);
        BARRIER(5);                  // allow ZB(t+2)=4 + ZA(t+2)=1; drains ZB(t+1)
    }
    {   // t = 46
        comp(ldsZA + (46 & 1) * ZA_BUF, ldsZB + (46 % 3) * ZB_BUF);
        convertZA(zreg, ldsZA + (47 & 1) * ZA_BUF);       // waits ZA(47): vmcnt(0)
        BARRIER(0);
    }
    comp(ldsZA + (47 & 1) * ZA_BUF, ldsZB + (47 % 3) * ZB_BUF);

    // ---- bias + LN stats (rows 0..31 local) ----
    float fzb[4], lng[4], lnb[4];
#pragma unroll
    for (int nj = 0; nj < 4; ++nj) {
        int o = wid * 64 + nj * 16 + l15;
        fzb[nj] = fz_b[o]; lng[nj] = ln_g[o]; lnb[nj] = ln_b[o];
    }
#pragma unroll
    for (int mi = 0; mi < 2; ++mi)
#pragma unroll
        for (int nj = 0; nj < 4; ++nj)
#pragma unroll
            for (int reg = 0; reg < 4; ++reg)
                acc[mi][nj][reg] += fzb[nj];

#pragma unroll
    for (int mi = 0; mi < 2; ++mi) {
#pragma unroll
        for (int reg = 0; reg < 4; ++reg) {
            float s = 0.f, q = 0.f;
#pragma unroll
            for (int nj = 0; nj < 4; ++nj) {
                float v = acc[mi][nj][reg];
                s += v; q += v * v;
            }
#pragma unroll
            for (int m = 0; m < 4; ++m) {
                s += __shfl_xor(s, 1 << m, 64);
                q += __shfl_xor(q, 1 << m, 64);
            }
            if (l15 == 0) {
                int row = mi * 16 + h * 4 + reg;
                redS[wid * 32 + row] = s;
                redQ[wid * 32 + row] = q;
            }
        }
    }
    __syncthreads();
    if (tid < 32) {
        float s = 0.f, q = 0.f;
#pragma unroll
        for (int w6 = 0; w6 < 6; ++w6) { s += redS[w6 * 32 + tid]; q += redQ[w6 * 32 + tid]; }
        float mu = s * (1.0f / 384.0f);
        float var = q * (1.0f / 384.0f) - mu * mu;
        mu_s[tid] = mu;
        rs_s[tid] = rsqrtf(var + EPSF);
    }
    __syncthreads();

    // ---- LN + gelu -> zpk[b][o][t] ----
#pragma unroll
    for (int mi = 0; mi < 2; ++mi)
#pragma unroll
        for (int nj = 0; nj < 4; ++nj) {
            int o = wid * 64 + nj * 16 + l15;
            u32* dst = (u32*)zpk + ((size_t)b * 384 + o) * 32 + th * 16 + mi * 8 + h * 2;
#pragma unroll
            for (int rp = 0; rp < 2; ++rp) {
                float zv[2];
#pragma unroll
                for (int k = 0; k < 2; ++k) {
                    int reg = rp * 2 + k;
                    int row = mi * 16 + h * 4 + reg;
                    float v = (acc[mi][nj][reg] - mu_s[row]) * rs_s[row] * lng[nj] + lnb[nj];
                    zv[k] = gelu_exact(v);
                }
                dst[rp] = (u32)f2bf(zv[0]) | ((u32)f2bf(zv[1]) << 16);
            }
        }
}

// ---------------------------------------------------------------------------
// kc5: implicit-GEMM cropped conv. grid (6 = conv*3+nh, 128 b), 512 thr = 8 waves.
// M=64 pix, N=128, K=6912 (216 steps). LDS 44.7 KB -> 3 blocks/CU.
// Single A buffer (republished per ec2), 4-slot B ring, counted vmcnt.
// Padded planes: B stride 2080 (128*16+32), A stride 2848 (176*16+32).
// ---------------------------------------------------------------------------
#define PB    2080
#define BBUF  (4 * PB)      // 8320
#define APL   2848
#define ABUF  (4 * APL)     // 11392

__global__ __launch_bounds__(512, 4) void kc5(const float* __restrict__ x_r,
                                              const float* __restrict__ x_i,
                                              const u16* __restrict__ Bw,
                                              const u16* __restrict__ zpk,
                                              const float* __restrict__ br,  const float* __restrict__ bnr_g,
                                              const float* __restrict__ bnr_b, const float* __restrict__ bnr_m,
                                              const float* __restrict__ bnr_v,
                                              const float* __restrict__ bi,  const float* __restrict__ bni_g,
                                              const float* __restrict__ bni_b, const float* __restrict__ bni_m,
                                              const float* __restrict__ bni_v,
                                              float* __restrict__ part) {
    const int q    = blockIdx.x;        // conv*3 + nh
    const int conv = q / 3;
    const int nh   = q % 3;
    const int b    = blockIdx.y;
    const int tid  = threadIdx.x;
    const int lane = tid & 63;
    const int wid  = tid >> 6;          // 0..7
    const int wm   = wid >> 2;          // 0..1 M-half
    const int wn   = wid & 3;           // 0..3 N-quarter
    const int l15  = lane & 15;
    const int h    = lane >> 4;         // 0..3

    __shared__ __align__(16) char lds[4 * BBUF + ABUF];   // 44672
    char* ldsB = lds;
    char* ldsA = lds + 4 * BBUF;
    __shared__ float redF[8];

    const float* x  = conv ? x_i : x_r;
    const float* xb = x + (size_t)b * (256 * 768);

    int boff[2];
#pragma unroll
    for (int nj = 0; nj < 2; ++nj) {
        int nl = wn * 32 + nj * 16 + l15;
        boff[nj] = h * PB + nl * 16;
    }
    int aoff[2];
#pragma unroll
    for (int mi = 0; mi < 2; ++mi) {
        int p = wm * 32 + mi * 16 + l15;
        int i = p >> 3, j = p & 7;
        aoff[mi] = h * APL + (i * 16 + j + 3) * 16;
    }

    // staging: wave w covers B plane h=w>>1, half w&1 (one gload16/thread)
    const int sh_   = wid >> 1;
    const int shalf = wid & 1;

    auto stageB = [&](int e2, int s2, char* buf) {
        size_t slot = ((size_t)conv * 864 + ((size_t)s2 * 24 + e2) * 4 + sh_) * 384
                      + nh * 128 + shalf * 64 + lane;
        gload16((const char*)Bw + slot * 16,
                buf + sh_ * PB + shalf * 1024 + lane * 16);
    };
    auto issueA = [&](int ec2, float4* ar) {       // 3 loads/thread, uniform (wrapped)
#pragma unroll
        for (int k = 0; k < 3; ++k) {
            int sl = tid + k * 512;
            if (sl >= 1408) sl -= 1408;
            int row = sl >> 3, qq = sl & 7;
            ar[k] = *(const float4*)(xb + (size_t)(48 + row) * 768 + ec2 * 32 + qq * 4);
        }
    };
    auto convertA = [&](const float4* ar, char* buf) {
#pragma unroll
        for (int k = 0; k < 3; ++k) {
            int sl = tid + k * 512;
            if (sl >= 1408) sl -= 1408;
            int row = sl >> 3, qq = sl & 7;
            ushort4 pk;
            pk.x = f2bf(ar[k].x); pk.y = f2bf(ar[k].y);
            pk.z = f2bf(ar[k].z); pk.w = f2bf(ar[k].w);
            *(ushort4*)(buf + (qq >> 1) * APL + row * 16 + (qq & 1) * 8) = pk;
        }
    };

    v4f acc[2][2] = {};

    auto comp = [&](int soff, char* curB) {
        v8bf a[2], bfv[2];
#pragma unroll
        for (int mi = 0; mi < 2; ++mi) a[mi] = *(const v8bf*)(ldsA + aoff[mi] + soff);
#pragma unroll
        for (int nj = 0; nj < 2; ++nj) bfv[nj] = *(const v8bf*)(curB + boff[nj]);
        __builtin_amdgcn_s_setprio(1);
#pragma unroll
        for (int mi = 0; mi < 2; ++mi)
#pragma unroll
            for (int nj = 0; nj < 2; ++nj)
                acc[mi][nj] = __builtin_amdgcn_mfma_f32_16x16x32_bf16(a[mi], bfv[nj], acc[mi][nj], 0, 0, 0);
        __builtin_amdgcn_s_setprio(0);
    };

    float4 areg[3];
    {   // prologue
        issueA(0, areg);
        stageB(0, 0, ldsB + 0 * BBUF);
        stageB(0, 1, ldsB + 1 * BBUF);
        stageB(0, 2, ldsB + 2 * BBUF);
        convertA(areg, ldsA);        // reg-dep waits areg
        BARRIER(2);                  // drain B(0); B(1),B(2) in flight
    }

#pragma unroll 1
    for (int ec2 = 0; ec2 < 24; ++ec2) {
        const bool last = (ec2 == 23);
#pragma unroll
        for (int s = 0; s < 9; ++s) {
            // stage B(g+3)
            if (!last || s <= 5) {
                int e2 = (s <= 5) ? ec2 : ec2 + 1;
                int s2 = (s <= 5) ? s + 3 : s - 6;
                stageB(e2, s2, ldsB + ((ec2 + s + 3) & 3) * BBUF);
            }
            if (s == 4 && !last) issueA(ec2 + 1, areg);
            comp(((s / 3) * 16 + (s % 3)) * 16, ldsB + ((ec2 + s) & 3) * BBUF);
            if (!last) {
                if (s <= 3)      BARRIER(2);   // drain B(g+1); B(g+2),B(g+3) fly
                else if (s <= 6) BARRIER(5);   // + areg(3) in flight
                else if (s == 7) BARRIER(2);   // drains areg + B(g+1)
                else {                          // s == 8
                    BARRIER(2);                 // drain B(g+1)
                    convertA(areg, ldsA);       // republish A (areg already retired)
                    BARRIER(2);                 // publish ds_writes (lgkmcnt(0))
                }
            } else {
                if (s <= 5)      BARRIER(2);
                else if (s == 6) BARRIER(1);
                else if (s == 7) BARRIER(0);
                else             __syncthreads();
            }
        }
    }

    // ---- BN + gelu + dot(zpk) ----
    const float* bcp = conv ? bi    : br;
    const float* gp  = conv ? bni_g : bnr_g;
    const float* bbp = conv ? bni_b : bnr_b;
    const float* mp  = conv ? bni_m : bnr_m;
    const float* vp  = conv ? bni_v : bnr_v;

    float sum = 0.f;
#pragma unroll
    for (int nj = 0; nj < 2; ++nj) {
        const int o = nh * 128 + wn * 32 + nj * 16 + l15;
        const float sc = gp[o] * rsqrtf(vp[o] + EPSF);
        const float sh2 = (bcp[o] - mp[o]) * sc + bbp[o];
        const u16* zb = zpk + ((size_t)b * 384 + o) * 64;
#pragma unroll
        for (int mi = 0; mi < 2; ++mi) {
            ushort4 zw = *(const ushort4*)(zb + wm * 32 + mi * 16 + h * 4);
#pragma unroll
            for (int reg = 0; reg < 4; ++reg) {
                float y = fmaf(acc[mi][nj][reg], sc, sh2);
                u16 zu = (reg == 0) ? zw.x : (reg == 1) ? zw.y : (reg == 2) ? zw.z : zw.w;
                sum = fmaf(gelu_exact(y), bf2f(zu), sum);
            }
        }
    }
#pragma unroll
    for (int off = 32; off >= 1; off >>= 1) sum += __shfl_down(sum, off, 64);

    if (lane == 0) redF[wid] = sum;
    __syncthreads();
    if (tid == 0) {
        float t = 0.f;
#pragma unroll
        for (int w8 = 0; w8 < 8; ++w8) t += redF[w8];
        part[((size_t)conv * 128 + b) * 3 + nh] = t;
    }
}

// ---------------------------------------------------------------------------
// kr: combine n-third partials, sigmoid.
// ---------------------------------------------------------------------------
__global__ __launch_bounds__(256) void kr(const float* __restrict__ part,
                                          const float* __restrict__ c,
                                          float* __restrict__ out) {
    int v = threadIdx.x;     // 0..255 = conv*128+b
    float s = part[v * 3] + part[v * 3 + 1] + part[v * 3 + 2];
    out[v] = 1.f / (1.f + expf(-s / c[0]));
}

extern "C" void kernel_launch(void* const* d_in, const int* in_sizes, int n_in,
                              void* d_out, int out_size, void* d_ws, size_t ws_size,
                              hipStream_t stream) {
    const float* z_r   = (const float*)d_in[0];
    const float* z_i   = (const float*)d_in[1];
    const float* x_r   = (const float*)d_in[2];
    const float* x_i   = (const float*)d_in[3];
    const float* fz_w  = (const float*)d_in[4];
    const float* fz_b  = (const float*)d_in[5];
    const float* ln_g  = (const float*)d_in[6];
    const float* ln_b  = (const float*)d_in[7];
    const float* wr    = (const float*)d_in[8];
    const float* br    = (const float*)d_in[9];
    const float* bnr_g = (const float*)d_in[10];
    const float* bnr_b = (const float*)d_in[11];
    const float* bnr_m = (const float*)d_in[12];
    const float* bnr_v = (const float*)d_in[13];
    const float* wi    = (const float*)d_in[14];
    const float* bi    = (const float*)d_in[15];
    const float* bni_g = (const float*)d_in[16];
    const float* bni_b = (const float*)d_in[17];
    const float* bni_m = (const float*)d_in[18];
    const float* bni_v = (const float*)d_in[19];
    const float* c     = (const float*)d_in[20];

    // ws (bytes): Bz [0, 1179648) | Bw [+10616832) | zpk [+6291456) | part [+3072)
    u16*   Bz   = (u16*)d_ws;
    u16*   Bw   = (u16*)((char*)d_ws + 1179648);
    u16*   zpk  = (u16*)((char*)d_ws + 1179648 + 10616832);
    float* part = (float*)((char*)d_ws + 1179648 + 10616832 + 6291456);

    kprep_z<<<288, 256, 0, stream>>>(fz_w, Bz);
    kprep_w<<<768, 256, 0, stream>>>(wr, wi, Bw);
    kz2<<<dim3(2, 128), 384, 0, stream>>>(z_r, z_i, Bz, fz_b, ln_g, ln_b, zpk);
    kc5<<<dim3(6, 128), 512, 0, stream>>>(x_r, x_i, Bw, zpk,
                                          br, bnr_g, bnr_b, bnr_m, bnr_v,
                                          bi, bni_g, bni_b, bni_m, bni_v,
                                          part);
    kr<<<1, 256, 0, stream>>>(part, c, (float*)d_out);
}